// Round 1
// baseline (1036.799 us; speedup 1.0000x reference)
//
#include <hip/hip_runtime.h>

#define NN 100000
#define NE 1600000
constexpr float EPS_BN = 1e-5f;
constexpr float ALPHA = 0.01f;
constexpr int NBLK = (NN + 255) / 256;      // 391
constexpr int GRID_GEMM = (NN + 63) / 64;   // 1563

// ---------------- init: zero counters & BN stats ----------------
__global__ void k_init(int* __restrict__ cnt, float* __restrict__ stats1, float* __restrict__ stats2) {
    int i = blockIdx.x * 256 + threadIdx.x;
    if (i < NN) cnt[i] = 0;
    if (i < 256) stats1[i] = 0.f;
    if (i < 512) stats2[i] = 0.f;
}

// ---------------- degree count (in-degree, excl self-loop) ----------------
__global__ void k_count(const int* __restrict__ dstv, int* __restrict__ cnt) {
    int e = blockIdx.x * 256 + threadIdx.x;
    if (e < NE) atomicAdd(&cnt[dstv[e]], 1);
}

__global__ void k_dinv(const int* __restrict__ cnt, float* __restrict__ dinv) {
    int i = blockIdx.x * 256 + threadIdx.x;
    if (i < NN) dinv[i] = rsqrtf((float)(cnt[i] + 1));   // +1 self loop, always > 0
}

// ---------------- scan (3-kernel) to build CSR indptr ----------------
__global__ void k_blocksum(const int* __restrict__ cnt, int* __restrict__ bsum) {
    __shared__ int red[256];
    int t = threadIdx.x;
    int i = blockIdx.x * 256 + t;
    red[t] = (i < NN) ? cnt[i] : 0;
    __syncthreads();
    for (int off = 128; off; off >>= 1) {
        if (t < off) red[t] += red[t + off];
        __syncthreads();
    }
    if (t == 0) bsum[blockIdx.x] = red[0];
}

__global__ void k_scanpartials(int* __restrict__ bsum, int nb) {
    __shared__ int tmp[512];
    int t = threadIdx.x;
    int v = (t < nb) ? bsum[t] : 0;
    tmp[t] = v;
    __syncthreads();
    for (int off = 1; off < 512; off <<= 1) {
        int u = (t >= off) ? tmp[t - off] : 0;
        __syncthreads();
        tmp[t] += u;
        __syncthreads();
    }
    if (t < nb) bsum[t] = tmp[t] - v;   // exclusive block offsets
}

__global__ void k_scanfinal(const int* __restrict__ cnt, const int* __restrict__ bsum,
                            int* __restrict__ indptr, int* __restrict__ pos) {
    __shared__ int tmp[256];
    int t = threadIdx.x;
    int i = blockIdx.x * 256 + t;
    int v = (i < NN) ? cnt[i] : 0;
    tmp[t] = v;
    __syncthreads();
    for (int off = 1; off < 256; off <<= 1) {
        int u = (t >= off) ? tmp[t - off] : 0;
        __syncthreads();
        tmp[t] += u;
        __syncthreads();
    }
    if (i < NN) {
        int ex = tmp[t] - v + bsum[blockIdx.x];
        indptr[i] = ex;
        pos[i] = ex;
    }
}

__global__ void k_fillcsr(const int* __restrict__ srcv, const int* __restrict__ dstv,
                          int* __restrict__ pos, int* __restrict__ col) {
    int e = blockIdx.x * 256 + threadIdx.x;
    if (e < NE) {
        int d = dstv[e];
        int p = atomicAdd(&pos[d], 1);
        col[p] = srcv[e];
    }
}

// ---------------- tiled fp32 GEMM with fused pre/post ops ----------------
// MODE 0: C = (A @ B) * dinv[row]                    (no A transform)
// MODE 1: C = (leaky(A*scale+shift) @ B) * dinv[row]
// MODE 2: C = (leaky(A*scale+shift) @ B) + bias[col]
template <int K, int M, int MODE>
__global__ __launch_bounds__(256) void k_gemm(
        const float* __restrict__ A, const float* __restrict__ B, float* __restrict__ C,
        const float* __restrict__ scale, const float* __restrict__ shift,
        const float* __restrict__ dinv, const float* __restrict__ bias) {
    constexpr int BN = 64, BK = 16, CPT = M / 16;
    __shared__ float As[BK][BN + 4];
    __shared__ float Bs[BK][M];
    __shared__ float s_sc[K];
    __shared__ float s_sh[K];

    int tid = threadIdx.x;
    if constexpr (MODE != 0) {
        for (int i = tid; i < K; i += 256) { s_sc[i] = scale[i]; s_sh[i] = shift[i]; }
    }
    __syncthreads();

    int lrow = tid >> 2;           // 0..63
    int lk   = (tid & 3) * 4;      // 0,4,8,12
    int arow = blockIdx.x * BN + lrow;
    const bool aok = arow < NN;
    int ty = tid >> 4, tx = tid & 15;

    float acc[4][CPT];
#pragma unroll
    for (int i = 0; i < 4; ++i)
#pragma unroll
        for (int j = 0; j < CPT; ++j) acc[i][j] = 0.f;

    for (int kk = 0; kk < K; kk += BK) {
        float4 av = make_float4(0.f, 0.f, 0.f, 0.f);
        if (aok) av = *(const float4*)(A + (size_t)arow * K + kk + lk);
        if constexpr (MODE != 0) {
            float* avp = &av.x;
#pragma unroll
            for (int j = 0; j < 4; ++j) {
                float v = avp[j] * s_sc[kk + lk + j] + s_sh[kk + lk + j];
                avp[j] = (v >= 0.f) ? v : ALPHA * v;
            }
        }
        As[lk + 0][lrow] = av.x;
        As[lk + 1][lrow] = av.y;
        As[lk + 2][lrow] = av.z;
        As[lk + 3][lrow] = av.w;
#pragma unroll
        for (int it = 0; it < M / 64; ++it) {
            int idx4 = tid + it * 256;
            int bk = idx4 / (M / 4);
            int bc = (idx4 % (M / 4)) * 4;
            *(float4*)&Bs[bk][bc] = *(const float4*)(B + (size_t)(kk + bk) * M + bc);
        }
        __syncthreads();
#pragma unroll
        for (int k = 0; k < BK; ++k) {
            float4 a4 = *(const float4*)&As[k][ty * 4];
            float a[4] = {a4.x, a4.y, a4.z, a4.w};
#pragma unroll
            for (int jb = 0; jb < CPT / 4; ++jb) {
                float4 b4 = *(const float4*)&Bs[k][jb * 64 + tx * 4];
                float bv[4] = {b4.x, b4.y, b4.z, b4.w};
#pragma unroll
                for (int i = 0; i < 4; ++i)
#pragma unroll
                    for (int j = 0; j < 4; ++j) acc[i][jb * 4 + j] += a[i] * bv[j];
            }
        }
        __syncthreads();
    }

#pragma unroll
    for (int i = 0; i < 4; ++i) {
        int row = blockIdx.x * BN + ty * 4 + i;
        if (row < NN) {
            float mul = 1.f;
            if constexpr (MODE != 2) mul = dinv[row];
#pragma unroll
            for (int jb = 0; jb < CPT / 4; ++jb) {
                int c0 = jb * 64 + tx * 4;
                float4 v;
                v.x = acc[i][jb * 4 + 0] * mul;
                v.y = acc[i][jb * 4 + 1] * mul;
                v.z = acc[i][jb * 4 + 2] * mul;
                v.w = acc[i][jb * 4 + 3] * mul;
                if constexpr (MODE == 2) {
                    v.x += bias[c0 + 0]; v.y += bias[c0 + 1];
                    v.z += bias[c0 + 2]; v.w += bias[c0 + 3];
                }
                *(float4*)(C + (size_t)row * M + c0) = v;
            }
        }
    }
}

// ---------------- CSR gather aggregation ----------------
// out[n] = (H[n] + sum_{s in neighbors(n)} H[s]) * dinv[n] + bias    (H already *dinv[src])
__global__ __launch_bounds__(64) void k_agg128(
        const float* __restrict__ H, const int* __restrict__ indptr, const int* __restrict__ cnt,
        const int* __restrict__ col, const float* __restrict__ dinv,
        const float* __restrict__ bias, float* __restrict__ out) {
    int n = blockIdx.x, t = threadIdx.x;
    const float2* H2 = (const float2*)H;
    __shared__ int sc[64];
    float2 acc = H2[(size_t)n * 64 + t];
    int start = indptr[n], c = cnt[n];
    for (int base = 0; base < c; base += 64) {
        int m = min(64, c - base);
        if (t < m) sc[t] = col[start + base + t];
        __syncthreads();
        for (int j = 0; j < m; ++j) {
            float2 v = H2[(size_t)sc[j] * 64 + t];
            acc.x += v.x; acc.y += v.y;
        }
        __syncthreads();
    }
    float dn = dinv[n];
    float2 b2 = ((const float2*)bias)[t];
    float2 o; o.x = acc.x * dn + b2.x; o.y = acc.y * dn + b2.y;
    ((float2*)out)[(size_t)n * 64 + t] = o;
}

__global__ __launch_bounds__(64) void k_agg256(
        const float* __restrict__ H, const int* __restrict__ indptr, const int* __restrict__ cnt,
        const int* __restrict__ col, const float* __restrict__ dinv,
        const float* __restrict__ bias, float* __restrict__ out) {
    int n = blockIdx.x, t = threadIdx.x;
    const float4* H4 = (const float4*)H;
    __shared__ int sc[64];
    float4 acc = H4[(size_t)n * 64 + t];
    int start = indptr[n], c = cnt[n];
    for (int base = 0; base < c; base += 64) {
        int m = min(64, c - base);
        if (t < m) sc[t] = col[start + base + t];
        __syncthreads();
        for (int j = 0; j < m; ++j) {
            float4 v = H4[(size_t)sc[j] * 64 + t];
            acc.x += v.x; acc.y += v.y; acc.z += v.z; acc.w += v.w;
        }
        __syncthreads();
    }
    float dn = dinv[n];
    float4 b4 = ((const float4*)bias)[t];
    float4 o;
    o.x = acc.x * dn + b4.x; o.y = acc.y * dn + b4.y;
    o.z = acc.z * dn + b4.z; o.w = acc.w * dn + b4.w;
    ((float4*)out)[(size_t)n * 64 + t] = o;
}

// ---------------- BN statistics (sum, sumsq per feature) ----------------
template <int M>
__global__ __launch_bounds__(256) void k_bnstats(const float* __restrict__ X, float* __restrict__ stats) {
    constexpr int R = 256 / M > 0 ? 256 / M : 1;   // rows per block-iter
    int f = threadIdx.x % M;
    int r0 = threadIdx.x / M;
    float s = 0.f, s2 = 0.f;
    for (int n = blockIdx.x * R + r0; n < NN; n += gridDim.x * R) {
        float v = X[(size_t)n * M + f];
        s += v; s2 += v * v;
    }
    atomicAdd(&stats[f], s);
    atomicAdd(&stats[M + f], s2);
}

__global__ void k_bnfinal(const float* __restrict__ stats, const float* __restrict__ g,
                          const float* __restrict__ be, float* __restrict__ scale,
                          float* __restrict__ shift, int M) {
    int f = blockIdx.x * 256 + threadIdx.x;
    if (f < M) {
        float mu = stats[f] * (1.f / NN);
        float var = stats[M + f] * (1.f / NN) - mu * mu;
        float r = rsqrtf(var + EPS_BN);
        float sc = g[f] * r;
        scale[f] = sc;
        shift[f] = be[f] - mu * sc;
    }
}

// ---------------- launch ----------------
extern "C" void kernel_launch(void* const* d_in, const int* in_sizes, int n_in,
                              void* d_out, int out_size, void* d_ws, size_t ws_size,
                              hipStream_t stream) {
    const float* emb = (const float*)d_in[0];
    const int* eidx  = (const int*)d_in[1];
    const float* W1  = (const float*)d_in[2];
    const float* b1  = (const float*)d_in[3];
    const float* g1  = (const float*)d_in[4];
    const float* be1 = (const float*)d_in[5];
    const float* W2  = (const float*)d_in[6];
    const float* b2  = (const float*)d_in[7];
    const float* g2  = (const float*)d_in[8];
    const float* be2 = (const float*)d_in[9];
    const float* Wf  = (const float*)d_in[10];
    const float* bf  = (const float*)d_in[11];
    float* out = (float*)d_out;
    const int* srcv = eidx;
    const int* dstv = eidx + NE;

    char* w = (char*)d_ws;
    auto alloc = [&](size_t bytes) {
        char* p = w;
        w += (bytes + 255) / 256 * 256;
        return p;
    };
    int* cnt     = (int*)alloc((size_t)NN * 4);
    int* indptr  = (int*)alloc((size_t)NN * 4);
    int* pos     = (int*)alloc((size_t)NN * 4);
    int* bsum    = (int*)alloc(512 * 4);
    int* col     = (int*)alloc((size_t)NE * 4);
    float* dinv  = (float*)alloc((size_t)NN * 4);
    float* stats1 = (float*)alloc(256 * 4);
    float* stats2 = (float*)alloc(512 * 4);
    float* sc1 = (float*)alloc(128 * 4);
    float* sh1 = (float*)alloc(128 * 4);
    float* sc2 = (float*)alloc(256 * 4);
    float* sh2 = (float*)alloc(256 * 4);
    float* H    = (float*)alloc((size_t)NN * 256 * 4);   // h1s (first half) then h2s (full)
    float* AGG1 = (float*)alloc((size_t)NN * 128 * 4);

    // graph preprocessing
    k_init<<<NBLK, 256, 0, stream>>>(cnt, stats1, stats2);
    k_count<<<(NE + 255) / 256, 256, 0, stream>>>(dstv, cnt);
    k_dinv<<<NBLK, 256, 0, stream>>>(cnt, dinv);
    k_blocksum<<<NBLK, 256, 0, stream>>>(cnt, bsum);
    k_scanpartials<<<1, 512, 0, stream>>>(bsum, NBLK);
    k_scanfinal<<<NBLK, 256, 0, stream>>>(cnt, bsum, indptr, pos);
    k_fillcsr<<<(NE + 255) / 256, 256, 0, stream>>>(srcv, dstv, pos, col);

    // layer 1: h1' = (emb @ W1) * dinv   -> H ; agg -> AGG1 ; BN1 stats
    k_gemm<64, 128, 0><<<GRID_GEMM, 256, 0, stream>>>(emb, W1, H, nullptr, nullptr, dinv, nullptr);
    k_agg128<<<NN, 64, 0, stream>>>(H, indptr, cnt, col, dinv, b1, AGG1);
    k_bnstats<128><<<256, 256, 0, stream>>>(AGG1, stats1);
    k_bnfinal<<<1, 256, 0, stream>>>(stats1, g1, be1, sc1, sh1, 128);

    // layer 2: h2' = (leaky(bn(AGG1)) @ W2) * dinv -> H ; agg -> out ; BN2 stats
    k_gemm<128, 256, 1><<<GRID_GEMM, 256, 0, stream>>>(AGG1, W2, H, sc1, sh1, dinv, nullptr);
    k_agg256<<<NN, 64, 0, stream>>>(H, indptr, cnt, col, dinv, b2, out);
    k_bnstats<256><<<256, 256, 0, stream>>>(out, stats2);
    k_bnfinal<<<1, 256, 0, stream>>>(stats2, g2, be2, sc2, sh2, 256);

    // final linear: out = leaky(bn(out)) @ Wf + bf   (A/C alias is per-block safe)
    k_gemm<256, 256, 2><<<GRID_GEMM, 256, 0, stream>>>(out, Wf, out, sc2, sh2, nullptr, bf);
}

// Round 2
// 851.893 us; speedup vs baseline: 1.2171x; 1.2171x over previous
//
#include <hip/hip_runtime.h>

#define NN 100000
#define NE 1600000
constexpr float EPS_BN = 1e-5f;
constexpr float ALPHA = 0.01f;
constexpr int NBLK = (NN + 255) / 256;      // 391

typedef __attribute__((ext_vector_type(8))) short short8;
typedef __attribute__((ext_vector_type(4))) float f32x4;

// ---- bf16 helpers (bit ops; bf16<<16 is exact) ----
__device__ __forceinline__ float bfu2f(uint lo16) {   // raw bf16 bits in low 16
    union { uint i; float f; } v; v.i = lo16 << 16; return v.f;
}
__device__ __forceinline__ float bfhi2f(uint u) {     // bf16 bits already in high 16
    union { uint i; float f; } v; v.i = u & 0xffff0000u; return v.f;
}
__device__ __forceinline__ ushort f2bf(float f) {     // RNE
    union { float f; uint i; } v; v.f = f;
    return (ushort)((v.i + 0x7fffu + ((v.i >> 16) & 1u)) >> 16);
}

// ---------------- init: zero counters & BN stats ----------------
__global__ void k_init(int* __restrict__ cnt, float* __restrict__ stats1, float* __restrict__ stats2) {
    int i = blockIdx.x * 256 + threadIdx.x;
    if (i < NN) cnt[i] = 0;
    if (i < 256) stats1[i] = 0.f;
    if (i < 512) stats2[i] = 0.f;
}

__global__ void k_count(const int* __restrict__ dstv, int* __restrict__ cnt) {
    int e = blockIdx.x * 256 + threadIdx.x;
    if (e < NE) atomicAdd(&cnt[dstv[e]], 1);
}

__global__ void k_dinv(const int* __restrict__ cnt, float* __restrict__ dinv) {
    int i = blockIdx.x * 256 + threadIdx.x;
    if (i < NN) dinv[i] = rsqrtf((float)(cnt[i] + 1));   // +1 self loop
}

// ---------------- scan to build CSR indptr ----------------
__global__ void k_blocksum(const int* __restrict__ cnt, int* __restrict__ bsum) {
    __shared__ int red[256];
    int t = threadIdx.x;
    int i = blockIdx.x * 256 + t;
    red[t] = (i < NN) ? cnt[i] : 0;
    __syncthreads();
    for (int off = 128; off; off >>= 1) {
        if (t < off) red[t] += red[t + off];
        __syncthreads();
    }
    if (t == 0) bsum[blockIdx.x] = red[0];
}

__global__ void k_scanpartials(int* __restrict__ bsum, int nb) {
    __shared__ int tmp[512];
    int t = threadIdx.x;
    int v = (t < nb) ? bsum[t] : 0;
    tmp[t] = v;
    __syncthreads();
    for (int off = 1; off < 512; off <<= 1) {
        int u = (t >= off) ? tmp[t - off] : 0;
        __syncthreads();
        tmp[t] += u;
        __syncthreads();
    }
    if (t < nb) bsum[t] = tmp[t] - v;
}

__global__ void k_scanfinal(const int* __restrict__ cnt, const int* __restrict__ bsum,
                            int* __restrict__ indptr, int* __restrict__ pos) {
    __shared__ int tmp[256];
    int t = threadIdx.x;
    int i = blockIdx.x * 256 + t;
    int v = (i < NN) ? cnt[i] : 0;
    tmp[t] = v;
    __syncthreads();
    for (int off = 1; off < 256; off <<= 1) {
        int u = (t >= off) ? tmp[t - off] : 0;
        __syncthreads();
        tmp[t] += u;
        __syncthreads();
    }
    if (i < NN) {
        int ex = tmp[t] - v + bsum[blockIdx.x];
        indptr[i] = ex;
        pos[i] = ex;
    }
}

__global__ void k_fillcsr(const int* __restrict__ srcv, const int* __restrict__ dstv,
                          int* __restrict__ pos, int* __restrict__ col) {
    int e = blockIdx.x * 256 + threadIdx.x;
    if (e < NE) {
        int d = dstv[e];
        int p = atomicAdd(&pos[d], 1);
        col[p] = srcv[e];
    }
}

// ---------------- weight convert + transpose: WT[m][k] = bf16(W[k][m]) ----------------
__global__ void k_wtrans(const float* __restrict__ W, ushort* __restrict__ WT, int K, int M) {
    int i = blockIdx.x * 256 + threadIdx.x;
    if (i < K * M) {
        int m = i / K, k = i % K;
        WT[i] = f2bf(W[(size_t)k * M + m]);
    }
}

// ---------------- MFMA bf16 GEMM with fused pre/post ops ----------------
// AT 0: A fp32 raw (convert to bf16 on stage)      AT 1: A bf16, apply leaky(A*sc+sh) on stage
// OUT 0: C = bf16( acc * dinv[row] )               OUT 1: C = fp32( acc + bias[col] )
// B is pre-transposed bf16 [NOUT][K].
template <int K, int NOUT, int AT, int OUT>
__global__ __launch_bounds__(256) void k_mgemm(
        const void* __restrict__ Ap, const ushort* __restrict__ BT, void* __restrict__ Cp,
        const float* __restrict__ scale, const float* __restrict__ shift,
        const float* __restrict__ dinv, const float* __restrict__ bias) {
    constexpr int BM = 128, BN = 64, BK = 32, LDA = 40;  // LDA pad: 2-way bank alias only (free)
    __shared__ ushort As[BM * LDA];
    __shared__ ushort Bs[BN * LDA];
    __shared__ float s_sc[K];
    __shared__ float s_sh[K];

    int tid = threadIdx.x;
    int brow = blockIdx.x * BM, bcol = blockIdx.y * BN;
    if constexpr (AT == 1) {
        for (int i = tid; i < K; i += 256) { s_sc[i] = scale[i]; s_sh[i] = shift[i]; }
        __syncthreads();
    }

    int lane = tid & 63, wid = tid >> 6;
    int wr = wid >> 1, wc = wid & 1;          // wave owns 64x32 of the 128x64 tile
    int fr = lane & 15, fq = lane >> 4;
    int fk = fq * 8;

    f32x4 acc[4][2];
#pragma unroll
    for (int mi = 0; mi < 4; ++mi)
#pragma unroll
        for (int ni = 0; ni < 2; ++ni) acc[mi][ni] = (f32x4){0.f, 0.f, 0.f, 0.f};

    const int srow = tid >> 1, sk0 = (tid & 1) * 16;   // A stage: 16 bf16 per thread
    const int grow = brow + srow;
    const int sbc = tid >> 2, sbk = (tid & 3) * 8;     // B stage: 8 bf16 per thread

    for (int kk = 0; kk < K; kk += BK) {
        __align__(16) ushort tmp[16];
#pragma unroll
        for (int j = 0; j < 16; ++j) tmp[j] = 0;
        if (grow < NN) {
            if constexpr (AT == 0) {
                const float* ap = (const float*)Ap + (size_t)grow * K + kk + sk0;
#pragma unroll
                for (int v4 = 0; v4 < 4; ++v4) {
                    float4 f = *(const float4*)(ap + v4 * 4);
                    tmp[v4 * 4 + 0] = f2bf(f.x);
                    tmp[v4 * 4 + 1] = f2bf(f.y);
                    tmp[v4 * 4 + 2] = f2bf(f.z);
                    tmp[v4 * 4 + 3] = f2bf(f.w);
                }
            } else {
                const ushort* ap = (const ushort*)Ap + (size_t)grow * K + kk + sk0;
                uint4 u0 = *(const uint4*)ap;
                uint4 u1 = *(const uint4*)(ap + 8);
                uint uu[8] = {u0.x, u0.y, u0.z, u0.w, u1.x, u1.y, u1.z, u1.w};
#pragma unroll
                for (int q = 0; q < 8; ++q) {
                    int kq = kk + sk0 + q * 2;
                    float e0 = bfu2f(uu[q] & 0xffffu) * s_sc[kq] + s_sh[kq];
                    float e1 = bfhi2f(uu[q]) * s_sc[kq + 1] + s_sh[kq + 1];
                    e0 = (e0 >= 0.f) ? e0 : ALPHA * e0;
                    e1 = (e1 >= 0.f) ? e1 : ALPHA * e1;
                    tmp[q * 2 + 0] = f2bf(e0);
                    tmp[q * 2 + 1] = f2bf(e1);
                }
            }
        }
        *(uint4*)&As[srow * LDA + sk0] = *(uint4*)&tmp[0];
        *(uint4*)&As[srow * LDA + sk0 + 8] = *(uint4*)&tmp[8];

        uint4 ub = *(const uint4*)(BT + (size_t)(bcol + sbc) * K + kk + sbk);
        *(uint4*)&Bs[sbc * LDA + sbk] = ub;

        __syncthreads();

        short8 af[4], bf[2];
#pragma unroll
        for (int mi = 0; mi < 4; ++mi)
            af[mi] = *(const short8*)&As[(wr * 64 + mi * 16 + fr) * LDA + fk];
#pragma unroll
        for (int ni = 0; ni < 2; ++ni)
            bf[ni] = *(const short8*)&Bs[(wc * 32 + ni * 16 + fr) * LDA + fk];
#pragma unroll
        for (int mi = 0; mi < 4; ++mi)
#pragma unroll
            for (int ni = 0; ni < 2; ++ni)
                acc[mi][ni] = __builtin_amdgcn_mfma_f32_16x16x32_bf16(af[mi], bf[ni], acc[mi][ni], 0, 0, 0);

        __syncthreads();
    }

    // epilogue: C row = brow + wr*64 + mi*16 + fq*4 + r ; col = bcol + wc*32 + ni*16 + fr
    if constexpr (OUT == 1) {
        float bv[2];
#pragma unroll
        for (int ni = 0; ni < 2; ++ni) bv[ni] = bias[bcol + wc * 32 + ni * 16 + fr];
        float* outf = (float*)Cp;
#pragma unroll
        for (int mi = 0; mi < 4; ++mi)
#pragma unroll
            for (int r = 0; r < 4; ++r) {
                int row = brow + wr * 64 + mi * 16 + fq * 4 + r;
                if (row < NN) {
#pragma unroll
                    for (int ni = 0; ni < 2; ++ni) {
                        int c = bcol + wc * 32 + ni * 16 + fr;
                        outf[(size_t)row * NOUT + c] = acc[mi][ni][r] + bv[ni];
                    }
                }
            }
    } else {
        ushort* outb = (ushort*)Cp;
#pragma unroll
        for (int mi = 0; mi < 4; ++mi)
#pragma unroll
            for (int r = 0; r < 4; ++r) {
                int row = brow + wr * 64 + mi * 16 + fq * 4 + r;
                if (row < NN) {
                    float dn = dinv[row];
#pragma unroll
                    for (int ni = 0; ni < 2; ++ni) {
                        int c = bcol + wc * 32 + ni * 16 + fr;
                        outb[(size_t)row * NOUT + c] = f2bf(acc[mi][ni][r] * dn);
                    }
                }
            }
    }
}

// ---------------- CSR gather aggregation (bf16 H, fp32 accum, bf16 out) ----------------
// out[n] = bf16( (H[n] + sum_{s in N(n)} H[s]) * dinv[n] + bias )
template <int M>
__global__ __launch_bounds__(64) void k_agg_bf(
        const ushort* __restrict__ H, const int* __restrict__ indptr, const int* __restrict__ cnt,
        const int* __restrict__ col, const float* __restrict__ dinv,
        const float* __restrict__ bias, ushort* __restrict__ outp) {
    int n = blockIdx.x, t = threadIdx.x;
    __shared__ int sc[64];
    int start = indptr[n], c = cnt[n];

    if constexpr (M == 256) {
        const uint2* H2 = (const uint2*)H;
        uint2 u = H2[(size_t)n * 64 + t];
        float a0 = bfu2f(u.x & 0xffffu), a1 = bfhi2f(u.x);
        float a2 = bfu2f(u.y & 0xffffu), a3 = bfhi2f(u.y);
        for (int base = 0; base < c; base += 64) {
            int m = min(64, c - base);
            if (t < m) sc[t] = col[start + base + t];
            __syncthreads();
#pragma unroll 4
            for (int j = 0; j < m; ++j) {
                uint2 v = H2[(size_t)sc[j] * 64 + t];
                a0 += bfu2f(v.x & 0xffffu); a1 += bfhi2f(v.x);
                a2 += bfu2f(v.y & 0xffffu); a3 += bfhi2f(v.y);
            }
            __syncthreads();
        }
        float dn = dinv[n];
        float4 b4 = ((const float4*)bias)[t];
        uint2 o;
        o.x = (uint)f2bf(a0 * dn + b4.x) | ((uint)f2bf(a1 * dn + b4.y) << 16);
        o.y = (uint)f2bf(a2 * dn + b4.z) | ((uint)f2bf(a3 * dn + b4.w) << 16);
        ((uint2*)outp)[(size_t)n * 64 + t] = o;
    } else {
        const uint* H1 = (const uint*)H;
        uint u = H1[(size_t)n * 64 + t];
        float a0 = bfu2f(u & 0xffffu), a1 = bfhi2f(u);
        for (int base = 0; base < c; base += 64) {
            int m = min(64, c - base);
            if (t < m) sc[t] = col[start + base + t];
            __syncthreads();
#pragma unroll 4
            for (int j = 0; j < m; ++j) {
                uint v = H1[(size_t)sc[j] * 64 + t];
                a0 += bfu2f(v & 0xffffu); a1 += bfhi2f(v);
            }
            __syncthreads();
        }
        float dn = dinv[n];
        float2 b2 = ((const float2*)bias)[t];
        uint o = (uint)f2bf(a0 * dn + b2.x) | ((uint)f2bf(a1 * dn + b2.y) << 16);
        ((uint*)outp)[(size_t)n * 64 + t] = o;
    }
}

// ---------------- BN statistics over bf16 input ----------------
template <int M>
__global__ __launch_bounds__(256) void k_bnstats_bf(const ushort* __restrict__ X, float* __restrict__ stats) {
    constexpr int FG = M / 4, RP = 256 / FG;
    int fg = threadIdx.x % FG, r0 = threadIdx.x / FG;
    float s0 = 0, s1 = 0, s2 = 0, s3 = 0, q0 = 0, q1 = 0, q2 = 0, q3 = 0;
    for (int n = blockIdx.x * RP + r0; n < NN; n += 256 * RP) {
        uint2 u = ((const uint2*)X)[(size_t)n * FG + fg];
        float v0 = bfu2f(u.x & 0xffffu), v1 = bfhi2f(u.x);
        float v2 = bfu2f(u.y & 0xffffu), v3 = bfhi2f(u.y);
        s0 += v0; q0 += v0 * v0;
        s1 += v1; q1 += v1 * v1;
        s2 += v2; q2 += v2 * v2;
        s3 += v3; q3 += v3 * v3;
    }
    int f0 = fg * 4;
    atomicAdd(&stats[f0 + 0], s0); atomicAdd(&stats[M + f0 + 0], q0);
    atomicAdd(&stats[f0 + 1], s1); atomicAdd(&stats[M + f0 + 1], q1);
    atomicAdd(&stats[f0 + 2], s2); atomicAdd(&stats[M + f0 + 2], q2);
    atomicAdd(&stats[f0 + 3], s3); atomicAdd(&stats[M + f0 + 3], q3);
}

__global__ void k_bnfinal(const float* __restrict__ stats, const float* __restrict__ g,
                          const float* __restrict__ be, float* __restrict__ scale,
                          float* __restrict__ shift, int M) {
    int f = blockIdx.x * 256 + threadIdx.x;
    if (f < M) {
        float mu = stats[f] * (1.f / NN);
        float var = stats[M + f] * (1.f / NN) - mu * mu;
        float r = rsqrtf(var + EPS_BN);
        float sc = g[f] * r;
        scale[f] = sc;
        shift[f] = be[f] - mu * sc;
    }
}

// ---------------- launch ----------------
extern "C" void kernel_launch(void* const* d_in, const int* in_sizes, int n_in,
                              void* d_out, int out_size, void* d_ws, size_t ws_size,
                              hipStream_t stream) {
    const float* emb = (const float*)d_in[0];
    const int* eidx  = (const int*)d_in[1];
    const float* W1  = (const float*)d_in[2];
    const float* b1  = (const float*)d_in[3];
    const float* g1  = (const float*)d_in[4];
    const float* be1 = (const float*)d_in[5];
    const float* W2  = (const float*)d_in[6];
    const float* b2  = (const float*)d_in[7];
    const float* g2  = (const float*)d_in[8];
    const float* be2 = (const float*)d_in[9];
    const float* Wf  = (const float*)d_in[10];
    const float* bf  = (const float*)d_in[11];
    float* out = (float*)d_out;
    const int* srcv = eidx;
    const int* dstv = eidx + NE;

    char* w = (char*)d_ws;
    auto alloc = [&](size_t bytes) {
        char* p = w;
        w += (bytes + 255) / 256 * 256;
        return p;
    };
    int* cnt      = (int*)alloc((size_t)NN * 4);
    int* indptr   = (int*)alloc((size_t)NN * 4);
    int* pos      = (int*)alloc((size_t)NN * 4);
    int* bsum     = (int*)alloc(512 * 4);
    int* colb     = (int*)alloc((size_t)NE * 4);
    float* dinv   = (float*)alloc((size_t)NN * 4);
    float* stats1 = (float*)alloc(256 * 4);
    float* stats2 = (float*)alloc(512 * 4);
    float* sc1 = (float*)alloc(128 * 4);
    float* sh1 = (float*)alloc(128 * 4);
    float* sc2 = (float*)alloc(256 * 4);
    float* sh2 = (float*)alloc(256 * 4);
    ushort* w1t = (ushort*)alloc((size_t)128 * 64 * 2);
    ushort* w2t = (ushort*)alloc((size_t)256 * 128 * 2);
    ushort* wft = (ushort*)alloc((size_t)256 * 256 * 2);
    ushort* H    = (ushort*)alloc((size_t)NN * 256 * 2);   // H1 (128-wide) then H2 (256-wide)
    ushort* AGG1 = (ushort*)alloc((size_t)NN * 128 * 2);
    ushort* AGG2 = (ushort*)alloc((size_t)NN * 256 * 2);

    // graph preprocessing
    k_init<<<NBLK, 256, 0, stream>>>(cnt, stats1, stats2);
    k_count<<<(NE + 255) / 256, 256, 0, stream>>>(dstv, cnt);
    k_dinv<<<NBLK, 256, 0, stream>>>(cnt, dinv);
    k_blocksum<<<NBLK, 256, 0, stream>>>(cnt, bsum);
    k_scanpartials<<<1, 512, 0, stream>>>(bsum, NBLK);
    k_scanfinal<<<NBLK, 256, 0, stream>>>(cnt, bsum, indptr, pos);
    k_fillcsr<<<(NE + 255) / 256, 256, 0, stream>>>(srcv, dstv, pos, colb);

    // weights -> bf16 transposed [M][K]
    k_wtrans<<<(64 * 128 + 255) / 256, 256, 0, stream>>>(W1, w1t, 64, 128);
    k_wtrans<<<(128 * 256 + 255) / 256, 256, 0, stream>>>(W2, w2t, 128, 256);
    k_wtrans<<<(256 * 256 + 255) / 256, 256, 0, stream>>>(Wf, wft, 256, 256);

    constexpr int GX = (NN + 127) / 128;   // 782

    // layer 1
    k_mgemm<64, 128, 0, 0><<<dim3(GX, 2), 256, 0, stream>>>(emb, w1t, H, nullptr, nullptr, dinv, nullptr);
    k_agg_bf<128><<<NN, 64, 0, stream>>>(H, indptr, cnt, colb, dinv, b1, AGG1);
    k_bnstats_bf<128><<<256, 256, 0, stream>>>(AGG1, stats1);
    k_bnfinal<<<1, 256, 0, stream>>>(stats1, g1, be1, sc1, sh1, 128);

    // layer 2
    k_mgemm<128, 256, 1, 0><<<dim3(GX, 4), 256, 0, stream>>>(AGG1, w2t, H, sc1, sh1, dinv, nullptr);
    k_agg_bf<256><<<NN, 64, 0, stream>>>(H, indptr, cnt, colb, dinv, b2, AGG2);
    k_bnstats_bf<256><<<256, 256, 0, stream>>>(AGG2, stats2);
    k_bnfinal<<<1, 256, 0, stream>>>(stats2, g2, be2, sc2, sh2, 256);

    // final linear -> fp32 d_out
    k_mgemm<256, 256, 1, 1><<<dim3(GX, 4), 256, 0, stream>>>(AGG2, wft, out, sc2, sh2, nullptr, bf);
}

// Round 3
// 604.306 us; speedup vs baseline: 1.7157x; 1.4097x over previous
//
#include <hip/hip_runtime.h>

#define NN 100000
#define NE 1600000
constexpr float EPS_BN = 1e-5f;
constexpr float ALPHA = 0.01f;
constexpr int NBLK = (NN + 255) / 256;      // 391
constexpr int GBN = 128;                    // bnpart grid

typedef __attribute__((ext_vector_type(8))) short short8;
typedef __attribute__((ext_vector_type(4))) float f32x4;

// ---- bf16 helpers (bit ops; bf16<<16 is exact) ----
__device__ __forceinline__ float bfu2f(uint lo16) {   // raw bf16 bits in low 16
    union { uint i; float f; } v; v.i = lo16 << 16; return v.f;
}
__device__ __forceinline__ float bfhi2f(uint u) {     // bf16 bits already in high 16
    union { uint i; float f; } v; v.i = u & 0xffff0000u; return v.f;
}
__device__ __forceinline__ ushort f2bf(float f) {     // RNE
    union { float f; uint i; } v; v.f = f;
    return (ushort)((v.i + 0x7fffu + ((v.i >> 16) & 1u)) >> 16);
}

// ---------------- init: zero counters ----------------
__global__ void k_init(int* __restrict__ cnt) {
    int i = blockIdx.x * 256 + threadIdx.x;
    if (i < NN) cnt[i] = 0;
}

__global__ void k_count(const int* __restrict__ dstv, int* __restrict__ cnt) {
    int e = blockIdx.x * 256 + threadIdx.x;
    if (e < NE) atomicAdd(&cnt[dstv[e]], 1);
}

__global__ void k_dinv(const int* __restrict__ cnt, float* __restrict__ dinv) {
    int i = blockIdx.x * 256 + threadIdx.x;
    if (i < NN) dinv[i] = rsqrtf((float)(cnt[i] + 1));   // +1 self loop
}

// ---------------- scan to build CSR indptr ----------------
__global__ void k_blocksum(const int* __restrict__ cnt, int* __restrict__ bsum) {
    __shared__ int red[256];
    int t = threadIdx.x;
    int i = blockIdx.x * 256 + t;
    red[t] = (i < NN) ? cnt[i] : 0;
    __syncthreads();
    for (int off = 128; off; off >>= 1) {
        if (t < off) red[t] += red[t + off];
        __syncthreads();
    }
    if (t == 0) bsum[blockIdx.x] = red[0];
}

__global__ void k_scanpartials(int* __restrict__ bsum, int nb) {
    __shared__ int tmp[512];
    int t = threadIdx.x;
    int v = (t < nb) ? bsum[t] : 0;
    tmp[t] = v;
    __syncthreads();
    for (int off = 1; off < 512; off <<= 1) {
        int u = (t >= off) ? tmp[t - off] : 0;
        __syncthreads();
        tmp[t] += u;
        __syncthreads();
    }
    if (t < nb) bsum[t] = tmp[t] - v;
}

__global__ void k_scanfinal(const int* __restrict__ cnt, const int* __restrict__ bsum,
                            int* __restrict__ indptr, int* __restrict__ pos) {
    __shared__ int tmp[256];
    int t = threadIdx.x;
    int i = blockIdx.x * 256 + t;
    int v = (i < NN) ? cnt[i] : 0;
    tmp[t] = v;
    __syncthreads();
    for (int off = 1; off < 256; off <<= 1) {
        int u = (t >= off) ? tmp[t - off] : 0;
        __syncthreads();
        tmp[t] += u;
        __syncthreads();
    }
    if (i < NN) {
        int ex = tmp[t] - v + bsum[blockIdx.x];
        indptr[i] = ex;
        pos[i] = ex;
    }
}

__global__ void k_fillcsr(const int* __restrict__ srcv, const int* __restrict__ dstv,
                          int* __restrict__ pos, int* __restrict__ col) {
    int e = blockIdx.x * 256 + threadIdx.x;
    if (e < NE) {
        int d = dstv[e];
        int p = atomicAdd(&pos[d], 1);
        col[p] = srcv[e];
    }
}

// ---------------- weight convert + transpose: WT[m][k] = bf16(W[k][m]) ----------------
__global__ void k_wtrans(const float* __restrict__ W, ushort* __restrict__ WT, int K, int M) {
    int i = blockIdx.x * 256 + threadIdx.x;
    if (i < K * M) {
        int m = i / K, k = i % K;
        WT[i] = f2bf(W[(size_t)k * M + m]);
    }
}

// ---------------- MFMA bf16 GEMM with fused pre/post ops ----------------
// AT 0: A fp32 raw (convert to bf16 on stage)      AT 1: A bf16, apply leaky(A*sc+sh) on stage
// OUT 0: C = bf16( acc * dinv[row] )               OUT 1: C = fp32( acc + bias[col] )
// B is pre-transposed bf16 [NOUT][K].
template <int K, int NOUT, int AT, int OUT>
__global__ __launch_bounds__(256) void k_mgemm(
        const void* __restrict__ Ap, const ushort* __restrict__ BT, void* __restrict__ Cp,
        const float* __restrict__ scale, const float* __restrict__ shift,
        const float* __restrict__ dinv, const float* __restrict__ bias) {
    constexpr int BM = 128, BN = 64, BK = 32, LDA = 40;  // LDA pad: 2-way bank alias only (free)
    __shared__ ushort As[BM * LDA];
    __shared__ ushort Bs[BN * LDA];
    __shared__ float s_sc[K];
    __shared__ float s_sh[K];

    int tid = threadIdx.x;
    int brow = blockIdx.x * BM, bcol = blockIdx.y * BN;
    if constexpr (AT == 1) {
        for (int i = tid; i < K; i += 256) { s_sc[i] = scale[i]; s_sh[i] = shift[i]; }
        __syncthreads();
    }

    int lane = tid & 63, wid = tid >> 6;
    int wr = wid >> 1, wc = wid & 1;          // wave owns 64x32 of the 128x64 tile
    int fr = lane & 15, fq = lane >> 4;
    int fk = fq * 8;

    f32x4 acc[4][2];
#pragma unroll
    for (int mi = 0; mi < 4; ++mi)
#pragma unroll
        for (int ni = 0; ni < 2; ++ni) acc[mi][ni] = (f32x4){0.f, 0.f, 0.f, 0.f};

    const int srow = tid >> 1, sk0 = (tid & 1) * 16;   // A stage: 16 bf16 per thread
    const int grow = brow + srow;
    const int sbc = tid >> 2, sbk = (tid & 3) * 8;     // B stage: 8 bf16 per thread

    for (int kk = 0; kk < K; kk += BK) {
        __align__(16) ushort tmp[16];
#pragma unroll
        for (int j = 0; j < 16; ++j) tmp[j] = 0;
        if (grow < NN) {
            if constexpr (AT == 0) {
                const float* ap = (const float*)Ap + (size_t)grow * K + kk + sk0;
#pragma unroll
                for (int v4 = 0; v4 < 4; ++v4) {
                    float4 f = *(const float4*)(ap + v4 * 4);
                    tmp[v4 * 4 + 0] = f2bf(f.x);
                    tmp[v4 * 4 + 1] = f2bf(f.y);
                    tmp[v4 * 4 + 2] = f2bf(f.z);
                    tmp[v4 * 4 + 3] = f2bf(f.w);
                }
            } else {
                const ushort* ap = (const ushort*)Ap + (size_t)grow * K + kk + sk0;
                uint4 u0 = *(const uint4*)ap;
                uint4 u1 = *(const uint4*)(ap + 8);
                uint uu[8] = {u0.x, u0.y, u0.z, u0.w, u1.x, u1.y, u1.z, u1.w};
#pragma unroll
                for (int q = 0; q < 8; ++q) {
                    int kq = kk + sk0 + q * 2;
                    float e0 = bfu2f(uu[q] & 0xffffu) * s_sc[kq] + s_sh[kq];
                    float e1 = bfhi2f(uu[q]) * s_sc[kq + 1] + s_sh[kq + 1];
                    e0 = (e0 >= 0.f) ? e0 : ALPHA * e0;
                    e1 = (e1 >= 0.f) ? e1 : ALPHA * e1;
                    tmp[q * 2 + 0] = f2bf(e0);
                    tmp[q * 2 + 1] = f2bf(e1);
                }
            }
        }
        *(uint4*)&As[srow * LDA + sk0] = *(uint4*)&tmp[0];
        *(uint4*)&As[srow * LDA + sk0 + 8] = *(uint4*)&tmp[8];

        uint4 ub = *(const uint4*)(BT + (size_t)(bcol + sbc) * K + kk + sbk);
        *(uint4*)&Bs[sbc * LDA + sbk] = ub;

        __syncthreads();

        short8 af[4], bf[2];
#pragma unroll
        for (int mi = 0; mi < 4; ++mi)
            af[mi] = *(const short8*)&As[(wr * 64 + mi * 16 + fr) * LDA + fk];
#pragma unroll
        for (int ni = 0; ni < 2; ++ni)
            bf[ni] = *(const short8*)&Bs[(wc * 32 + ni * 16 + fr) * LDA + fk];
#pragma unroll
        for (int mi = 0; mi < 4; ++mi)
#pragma unroll
            for (int ni = 0; ni < 2; ++ni)
                acc[mi][ni] = __builtin_amdgcn_mfma_f32_16x16x32_bf16(af[mi], bf[ni], acc[mi][ni], 0, 0, 0);

        __syncthreads();
    }

    // epilogue: C row = brow + wr*64 + mi*16 + fq*4 + r ; col = bcol + wc*32 + ni*16 + fr
    if constexpr (OUT == 1) {
        float bv[2];
#pragma unroll
        for (int ni = 0; ni < 2; ++ni) bv[ni] = bias[bcol + wc * 32 + ni * 16 + fr];
        float* outf = (float*)Cp;
#pragma unroll
        for (int mi = 0; mi < 4; ++mi)
#pragma unroll
            for (int r = 0; r < 4; ++r) {
                int row = brow + wr * 64 + mi * 16 + fq * 4 + r;
                if (row < NN) {
#pragma unroll
                    for (int ni = 0; ni < 2; ++ni) {
                        int c = bcol + wc * 32 + ni * 16 + fr;
                        outf[(size_t)row * NOUT + c] = acc[mi][ni][r] + bv[ni];
                    }
                }
            }
    } else {
        ushort* outb = (ushort*)Cp;
#pragma unroll
        for (int mi = 0; mi < 4; ++mi)
#pragma unroll
            for (int r = 0; r < 4; ++r) {
                int row = brow + wr * 64 + mi * 16 + fq * 4 + r;
                if (row < NN) {
                    float dn = dinv[row];
#pragma unroll
                    for (int ni = 0; ni < 2; ++ni) {
                        int c = bcol + wc * 32 + ni * 16 + fr;
                        outb[(size_t)row * NOUT + c] = f2bf(acc[mi][ni][r] * dn);
                    }
                }
            }
    }
}

// ---------------- CSR gather aggregation (bf16 H, fp32 accum, bf16 out) ----------------
// out[n] = bf16( (H[n] + sum_{s in N(n)} H[s]) * dinv[n] + bias )
template <int M>
__global__ __launch_bounds__(64) void k_agg_bf(
        const ushort* __restrict__ H, const int* __restrict__ indptr, const int* __restrict__ cnt,
        const int* __restrict__ col, const float* __restrict__ dinv,
        const float* __restrict__ bias, ushort* __restrict__ outp) {
    int n = blockIdx.x, t = threadIdx.x;
    __shared__ int sc[64];
    int start = indptr[n], c = cnt[n];

    if constexpr (M == 256) {
        const uint2* H2 = (const uint2*)H;
        uint2 u = H2[(size_t)n * 64 + t];
        float a0 = bfu2f(u.x & 0xffffu), a1 = bfhi2f(u.x);
        float a2 = bfu2f(u.y & 0xffffu), a3 = bfhi2f(u.y);
        for (int base = 0; base < c; base += 64) {
            int m = min(64, c - base);
            if (t < m) sc[t] = col[start + base + t];
            __syncthreads();
#pragma unroll 4
            for (int j = 0; j < m; ++j) {
                uint2 v = H2[(size_t)sc[j] * 64 + t];
                a0 += bfu2f(v.x & 0xffffu); a1 += bfhi2f(v.x);
                a2 += bfu2f(v.y & 0xffffu); a3 += bfhi2f(v.y);
            }
            __syncthreads();
        }
        float dn = dinv[n];
        float4 b4 = ((const float4*)bias)[t];
        uint2 o;
        o.x = (uint)f2bf(a0 * dn + b4.x) | ((uint)f2bf(a1 * dn + b4.y) << 16);
        o.y = (uint)f2bf(a2 * dn + b4.z) | ((uint)f2bf(a3 * dn + b4.w) << 16);
        ((uint2*)outp)[(size_t)n * 64 + t] = o;
    } else {
        const uint* H1 = (const uint*)H;
        uint u = H1[(size_t)n * 64 + t];
        float a0 = bfu2f(u & 0xffffu), a1 = bfhi2f(u);
        for (int base = 0; base < c; base += 64) {
            int m = min(64, c - base);
            if (t < m) sc[t] = col[start + base + t];
            __syncthreads();
#pragma unroll 4
            for (int j = 0; j < m; ++j) {
                uint v = H1[(size_t)sc[j] * 64 + t];
                a0 += bfu2f(v & 0xffffu); a1 += bfhi2f(v);
            }
            __syncthreads();
        }
        float dn = dinv[n];
        float2 b2 = ((const float2*)bias)[t];
        uint o = (uint)f2bf(a0 * dn + b2.x) | ((uint)f2bf(a1 * dn + b2.y) << 16);
        ((uint*)outp)[(size_t)n * 64 + t] = o;
    }
}

// ---------------- BN statistics: stage 1 partials (atomic-free) ----------------
template <int M>
__global__ __launch_bounds__(256) void k_bnpart(const ushort* __restrict__ X, float* __restrict__ partials) {
    constexpr int FG = M / 4, RP = 256 / FG;
    __shared__ float rs[RP * M];
    __shared__ float rq[RP * M];
    int fg = threadIdx.x % FG, r0 = threadIdx.x / FG;
    float s0 = 0, s1 = 0, s2 = 0, s3 = 0, q0 = 0, q1 = 0, q2 = 0, q3 = 0;
    for (int n = blockIdx.x * RP + r0; n < NN; n += GBN * RP) {
        uint2 u = ((const uint2*)X)[(size_t)n * FG + fg];
        float v0 = bfu2f(u.x & 0xffffu), v1 = bfhi2f(u.x);
        float v2 = bfu2f(u.y & 0xffffu), v3 = bfhi2f(u.y);
        s0 += v0; q0 += v0 * v0;
        s1 += v1; q1 += v1 * v1;
        s2 += v2; q2 += v2 * v2;
        s3 += v3; q3 += v3 * v3;
    }
    int f0 = fg * 4;
    rs[r0 * M + f0 + 0] = s0; rq[r0 * M + f0 + 0] = q0;
    rs[r0 * M + f0 + 1] = s1; rq[r0 * M + f0 + 1] = q1;
    rs[r0 * M + f0 + 2] = s2; rq[r0 * M + f0 + 2] = q2;
    rs[r0 * M + f0 + 3] = s3; rq[r0 * M + f0 + 3] = q3;
    __syncthreads();
    for (int h = RP / 2; h; h >>= 1) {
        if (r0 < h) {
#pragma unroll
            for (int j = 0; j < 4; ++j) {
                rs[r0 * M + f0 + j] += rs[(r0 + h) * M + f0 + j];
                rq[r0 * M + f0 + j] += rq[(r0 + h) * M + f0 + j];
            }
        }
        __syncthreads();
    }
    if (threadIdx.x < M) {
        partials[(size_t)blockIdx.x * 2 * M + threadIdx.x] = rs[threadIdx.x];
        partials[(size_t)blockIdx.x * 2 * M + M + threadIdx.x] = rq[threadIdx.x];
    }
}

// ---------------- BN stage 2: reduce partials -> scale/shift ----------------
template <int M>
__global__ void k_bnred(const float* __restrict__ partials, const float* __restrict__ g,
                        const float* __restrict__ be, float* __restrict__ scale,
                        float* __restrict__ shift) {
    int f = threadIdx.x;
    if (f < M) {
        float s = 0.f, q = 0.f;
        for (int b = 0; b < GBN; ++b) {
            s += partials[(size_t)b * 2 * M + f];
            q += partials[(size_t)b * 2 * M + M + f];
        }
        float mu = s * (1.f / NN);
        float var = q * (1.f / NN) - mu * mu;
        float r = rsqrtf(var + EPS_BN);
        float sc = g[f] * r;
        scale[f] = sc;
        shift[f] = be[f] - mu * sc;
    }
}

// ---------------- launch ----------------
extern "C" void kernel_launch(void* const* d_in, const int* in_sizes, int n_in,
                              void* d_out, int out_size, void* d_ws, size_t ws_size,
                              hipStream_t stream) {
    const float* emb = (const float*)d_in[0];
    const int* eidx  = (const int*)d_in[1];
    const float* W1  = (const float*)d_in[2];
    const float* b1  = (const float*)d_in[3];
    const float* g1  = (const float*)d_in[4];
    const float* be1 = (const float*)d_in[5];
    const float* W2  = (const float*)d_in[6];
    const float* b2  = (const float*)d_in[7];
    const float* g2  = (const float*)d_in[8];
    const float* be2 = (const float*)d_in[9];
    const float* Wf  = (const float*)d_in[10];
    const float* bf  = (const float*)d_in[11];
    float* out = (float*)d_out;
    const int* srcv = eidx;
    const int* dstv = eidx + NE;

    char* w = (char*)d_ws;
    auto alloc = [&](size_t bytes) {
        char* p = w;
        w += (bytes + 255) / 256 * 256;
        return p;
    };
    int* cnt      = (int*)alloc((size_t)NN * 4);
    int* indptr   = (int*)alloc((size_t)NN * 4);
    int* pos      = (int*)alloc((size_t)NN * 4);
    int* bsum     = (int*)alloc(512 * 4);
    int* colb     = (int*)alloc((size_t)NE * 4);
    float* dinv   = (float*)alloc((size_t)NN * 4);
    float* partials = (float*)alloc((size_t)GBN * 512 * 4);
    float* sc1 = (float*)alloc(128 * 4);
    float* sh1 = (float*)alloc(128 * 4);
    float* sc2 = (float*)alloc(256 * 4);
    float* sh2 = (float*)alloc(256 * 4);
    ushort* w1t = (ushort*)alloc((size_t)128 * 64 * 2);
    ushort* w2t = (ushort*)alloc((size_t)256 * 128 * 2);
    ushort* wft = (ushort*)alloc((size_t)256 * 256 * 2);
    ushort* H    = (ushort*)alloc((size_t)NN * 256 * 2);   // H1 (128-wide) then H2 (256-wide)
    ushort* AGG1 = (ushort*)alloc((size_t)NN * 128 * 2);
    ushort* AGG2 = (ushort*)alloc((size_t)NN * 256 * 2);

    // graph preprocessing
    k_init<<<NBLK, 256, 0, stream>>>(cnt);
    k_count<<<(NE + 255) / 256, 256, 0, stream>>>(dstv, cnt);
    k_dinv<<<NBLK, 256, 0, stream>>>(cnt, dinv);
    k_blocksum<<<NBLK, 256, 0, stream>>>(cnt, bsum);
    k_scanpartials<<<1, 512, 0, stream>>>(bsum, NBLK);
    k_scanfinal<<<NBLK, 256, 0, stream>>>(cnt, bsum, indptr, pos);
    k_fillcsr<<<(NE + 255) / 256, 256, 0, stream>>>(srcv, dstv, pos, colb);

    // weights -> bf16 transposed [M][K]
    k_wtrans<<<(64 * 128 + 255) / 256, 256, 0, stream>>>(W1, w1t, 64, 128);
    k_wtrans<<<(128 * 256 + 255) / 256, 256, 0, stream>>>(W2, w2t, 128, 256);
    k_wtrans<<<(256 * 256 + 255) / 256, 256, 0, stream>>>(Wf, wft, 256, 256);

    constexpr int GX = (NN + 127) / 128;   // 782

    // layer 1
    k_mgemm<64, 128, 0, 0><<<dim3(GX, 2), 256, 0, stream>>>(emb, w1t, H, nullptr, nullptr, dinv, nullptr);
    k_agg_bf<128><<<NN, 64, 0, stream>>>(H, indptr, cnt, colb, dinv, b1, AGG1);
    k_bnpart<128><<<GBN, 256, 0, stream>>>(AGG1, partials);
    k_bnred<128><<<1, 256, 0, stream>>>(partials, g1, be1, sc1, sh1);

    // layer 2
    k_mgemm<128, 256, 1, 0><<<dim3(GX, 4), 256, 0, stream>>>(AGG1, w2t, H, sc1, sh1, dinv, nullptr);
    k_agg_bf<256><<<NN, 64, 0, stream>>>(H, indptr, cnt, colb, dinv, b2, AGG2);
    k_bnpart<256><<<GBN, 256, 0, stream>>>(AGG2, partials);
    k_bnred<256><<<1, 256, 0, stream>>>(partials, g2, be2, sc2, sh2);

    // final linear -> fp32 d_out
    k_mgemm<256, 256, 1, 1><<<dim3(GX, 4), 256, 0, stream>>>(AGG2, wft, out, sc2, sh2, nullptr, bf);
}

// Round 4
// 432.137 us; speedup vs baseline: 2.3992x; 1.3984x over previous
//
#include <hip/hip_runtime.h>

#define NN 100000
#define NE 1600000
constexpr float EPS_BN = 1e-5f;
constexpr float ALPHA = 0.01f;
constexpr int NBLK = (NN + 255) / 256;      // 391
constexpr int GBN = 128;                    // bnpart grid
constexpr int NBUCK = (NN + 127) / 128;     // 782 buckets of 128 nodes
constexpr int GA = 128;                     // bucket-pass blocks
constexpr int EPB = NE / GA;                // 12500 edges/block (exact)

typedef __attribute__((ext_vector_type(8))) short short8;
typedef __attribute__((ext_vector_type(4))) float f32x4;

// ---- bf16 helpers ----
__device__ __forceinline__ float bfu2f(uint lo16) {
    union { uint i; float f; } v; v.i = lo16 << 16; return v.f;
}
__device__ __forceinline__ float bfhi2f(uint u) {
    union { uint i; float f; } v; v.i = u & 0xffff0000u; return v.f;
}
__device__ __forceinline__ ushort f2bf(float f) {     // RNE
    union { float f; uint i; } v; v.f = f;
    return (ushort)((v.i + 0x7fffu + ((v.i >> 16) & 1u)) >> 16);
}

// ================= bucketed CSR build =================
// A0: per-block histogram over dst buckets (dst>>7)
__global__ __launch_bounds__(256) void k_bhist(const int* __restrict__ dstv, int* __restrict__ bcnt) {
    __shared__ int hist[NBUCK];
    for (int i = threadIdx.x; i < NBUCK; i += 256) hist[i] = 0;
    __syncthreads();
    int base = blockIdx.x * EPB;
    for (int i = threadIdx.x; i < EPB; i += 256)
        atomicAdd(&hist[dstv[base + i] >> 7], 1);
    __syncthreads();
    for (int i = threadIdx.x; i < NBUCK; i += 256)
        bcnt[i * GA + blockIdx.x] = hist[i];
}

// scan: bucket totals -> bucket bases + per-(bucket,block) cursors
__global__ __launch_bounds__(1024) void k_bscan(const int* __restrict__ bcnt,
                                                int* __restrict__ gcur, int* __restrict__ bbase) {
    __shared__ int tot[1024];
    int b = threadIdx.x;
    int t = 0;
    if (b < NBUCK)
        for (int k = 0; k < GA; ++k) t += bcnt[b * GA + k];
    tot[b] = t;
    __syncthreads();
    for (int off = 1; off < 1024; off <<= 1) {
        int u = (b >= off) ? tot[b - off] : 0;
        __syncthreads();
        tot[b] += u;
        __syncthreads();
    }
    int ex = tot[b] - t;   // exclusive
    if (b < NBUCK) {
        bbase[b] = ex;
        int cur = ex;
        for (int k = 0; k < GA; ++k) { gcur[b * GA + k] = cur; cur += bcnt[b * GA + k]; }
    }
    if (b == 0) bbase[NBUCK] = NE;
}

// A1: scatter edges into bucket-ordered array, packed (dst_local<<17 | src)
__global__ __launch_bounds__(256) void k_bscatter(const int* __restrict__ srcv, const int* __restrict__ dstv,
                                                  const int* __restrict__ gcur, uint* __restrict__ bpair) {
    __shared__ int lcur[NBUCK];
    for (int i = threadIdx.x; i < NBUCK; i += 256) lcur[i] = gcur[i * GA + blockIdx.x];
    __syncthreads();
    int base = blockIdx.x * EPB;
    for (int i = threadIdx.x; i < EPB; i += 256) {
        int d = dstv[base + i], s = srcv[base + i];
        int slot = atomicAdd(&lcur[d >> 7], 1);
        bpair[slot] = ((uint)(d & 127) << 17) | (uint)s;
    }
}

// B: per-bucket -> CSR col + degrees + indptr
__global__ __launch_bounds__(256) void k_bcsr(const uint* __restrict__ bpair, const int* __restrict__ bbase,
                                              int* __restrict__ col, int* __restrict__ cnt,
                                              int* __restrict__ indptr) {
    __shared__ int h[128];
    __shared__ int off[128];
    int b = blockIdx.x, t = threadIdx.x;
    int p0 = bbase[b], p1 = bbase[b + 1];
    if (t < 128) h[t] = 0;
    __syncthreads();
    for (int i = p0 + t; i < p1; i += 256)
        atomicAdd(&h[bpair[i] >> 17], 1);
    __syncthreads();
    if (t < 128) off[t] = h[t];
    __syncthreads();
    for (int o = 1; o < 128; o <<= 1) {
        int u = 0;
        if (t < 128 && t >= o) u = off[t - o];
        __syncthreads();
        if (t < 128) off[t] += u;
        __syncthreads();
    }
    if (t < 128) {
        int st = p0 + off[t] - h[t];           // exclusive within bucket + bucket base
        int node = b * 128 + t;
        if (node < NN) { indptr[node] = st; cnt[node] = h[t]; }
        off[t] = st;                           // reuse as scatter cursor
    }
    __syncthreads();
    for (int i = p0 + t; i < p1; i += 256) {
        uint u = bpair[i];
        int slot = atomicAdd(&off[u >> 17], 1);
        col[slot] = (int)(u & 0x1FFFFu);
    }
}

__global__ void k_dinv(const int* __restrict__ cnt, float* __restrict__ dinv) {
    int i = blockIdx.x * 256 + threadIdx.x;
    if (i < NN) dinv[i] = rsqrtf((float)(cnt[i] + 1));   // +1 self loop
}

// ================= weights -> bf16 transposed [M][K] =================
__global__ void k_wtrans(const float* __restrict__ W, ushort* __restrict__ WT, int K, int M) {
    int i = blockIdx.x * 256 + threadIdx.x;
    if (i < K * M) {
        int m = i / K, k = i % K;
        WT[i] = f2bf(W[(size_t)k * M + m]);
    }
}

// ================= elementwise pre-passes =================
// embs = bf16(emb * dinv[row])   (64-wide)
__global__ __launch_bounds__(256) void k_semb(const float* __restrict__ emb, const float* __restrict__ dinv,
                                              uint2* __restrict__ embs) {
    int i = blockIdx.x * 256 + threadIdx.x;   // uint2 index: 4 feats
    if (i >= NN * 16) return;
    int row = i >> 4;
    float dn = dinv[row];
    float4 f = ((const float4*)emb)[i];
    uint2 o;
    o.x = (uint)f2bf(f.x * dn) | ((uint)f2bf(f.y * dn) << 16);
    o.y = (uint)f2bf(f.z * dn) | ((uint)f2bf(f.w * dn) << 16);
    embs[i] = o;
}

// x2s = bf16( leaky(sc*H1+sh) * dinv[row] )   (128-wide)
__global__ __launch_bounds__(256) void k_x2s(const ushort* __restrict__ H1, const float* __restrict__ sc,
                                             const float* __restrict__ sh, const float* __restrict__ dinv,
                                             ushort* __restrict__ x2s) {
    int i = blockIdx.x * 256 + threadIdx.x;   // uint4 index: 8 feats
    if (i >= NN * 16) return;
    int row = i >> 4, f0 = (i & 15) * 8;
    float dn = dinv[row];
    uint4 u = ((const uint4*)H1)[i];
    uint uu[4] = {u.x, u.y, u.z, u.w};
    uint oo[4];
#pragma unroll
    for (int q = 0; q < 4; ++q) {
        int f = f0 + q * 2;
        float e0 = bfu2f(uu[q] & 0xffffu) * sc[f] + sh[f];
        float e1 = bfhi2f(uu[q]) * sc[f + 1] + sh[f + 1];
        e0 = ((e0 >= 0.f) ? e0 : ALPHA * e0) * dn;
        e1 = ((e1 >= 0.f) ? e1 : ALPHA * e1) * dn;
        oo[q] = (uint)f2bf(e0) | ((uint)f2bf(e1) << 16);
    }
    uint4 o; o.x = oo[0]; o.y = oo[1]; o.z = oo[2]; o.w = oo[3];
    ((uint4*)x2s)[i] = o;
}

// ================= CSR gather aggregation (bf16, fp32 accum) =================
// out[n] = bf16( (X[n] + sum_{s in N(n)} X[s]) * dinv[n] )
template <int W>
__global__ __launch_bounds__(64) void k_agg(const ushort* __restrict__ X, const int* __restrict__ indptr,
                                            const int* __restrict__ cnt, const int* __restrict__ col,
                                            const float* __restrict__ dinv, ushort* __restrict__ out) {
    int n = blockIdx.x, t = threadIdx.x;
    __shared__ int sc[64];
    int start = indptr[n], c = cnt[n];
    if constexpr (W == 64) {
        float a0 = bfu2f(X[(size_t)n * 64 + t]);
        for (int base = 0; base < c; base += 64) {
            int m = min(64, c - base);
            if (t < m) sc[t] = col[start + base + t];
            __syncthreads();
#pragma unroll 4
            for (int j = 0; j < m; ++j)
                a0 += bfu2f(X[(size_t)sc[j] * 64 + t]);
            __syncthreads();
        }
        out[(size_t)n * 64 + t] = f2bf(a0 * dinv[n]);
    } else {   // W == 128
        const uint* Xu = (const uint*)X;
        uint u = Xu[(size_t)n * 64 + t];
        float a0 = bfu2f(u & 0xffffu), a1 = bfhi2f(u);
        for (int base = 0; base < c; base += 64) {
            int m = min(64, c - base);
            if (t < m) sc[t] = col[start + base + t];
            __syncthreads();
#pragma unroll 4
            for (int j = 0; j < m; ++j) {
                uint v = Xu[(size_t)sc[j] * 64 + t];
                a0 += bfu2f(v & 0xffffu); a1 += bfhi2f(v);
            }
            __syncthreads();
        }
        float dn = dinv[n];
        ((uint*)out)[(size_t)n * 64 + t] = (uint)f2bf(a0 * dn) | ((uint)f2bf(a1 * dn) << 16);
    }
}

// ================= MFMA bf16 GEMM =================
// AT 1: A bf16, apply leaky(A*sc+sh) on stage     AT 2: A bf16 raw
// OUT 1: C = fp32( acc + bias[col] )              OUT 2: C = bf16( acc + bias[col] )
template <int K, int NOUT, int AT, int OUT>
__global__ __launch_bounds__(256) void k_mgemm(
        const void* __restrict__ Ap, const ushort* __restrict__ BT, void* __restrict__ Cp,
        const float* __restrict__ scale, const float* __restrict__ shift,
        const float* __restrict__ bias) {
    constexpr int BM = 128, BN = 64, BK = 32, LDA = 40;
    __shared__ ushort As[BM * LDA];
    __shared__ ushort Bs[BN * LDA];
    __shared__ float s_sc[K];
    __shared__ float s_sh[K];

    int tid = threadIdx.x;
    int brow = blockIdx.x * BM, bcol = blockIdx.y * BN;
    if constexpr (AT == 1) {
        for (int i = tid; i < K; i += 256) { s_sc[i] = scale[i]; s_sh[i] = shift[i]; }
        __syncthreads();
    }

    int lane = tid & 63, wid = tid >> 6;
    int wr = wid >> 1, wc = wid & 1;
    int fr = lane & 15, fq = lane >> 4;
    int fk = fq * 8;

    f32x4 acc[4][2];
#pragma unroll
    for (int mi = 0; mi < 4; ++mi)
#pragma unroll
        for (int ni = 0; ni < 2; ++ni) acc[mi][ni] = (f32x4){0.f, 0.f, 0.f, 0.f};

    const int srow = tid >> 1, sk0 = (tid & 1) * 16;
    const int grow = brow + srow;
    const bool aok = grow < NN;
    const int sbc = tid >> 2, sbk = (tid & 3) * 8;

    for (int kk = 0; kk < K; kk += BK) {
        __align__(16) ushort tmp[16];
#pragma unroll
        for (int j = 0; j < 16; ++j) tmp[j] = 0;
        if (aok) {
            const ushort* ap = (const ushort*)Ap + (size_t)grow * K + kk + sk0;
            if constexpr (AT == 2) {
                *(uint4*)&tmp[0] = *(const uint4*)ap;
                *(uint4*)&tmp[8] = *(const uint4*)(ap + 8);
            } else {
                uint4 u0 = *(const uint4*)ap;
                uint4 u1 = *(const uint4*)(ap + 8);
                uint uu[8] = {u0.x, u0.y, u0.z, u0.w, u1.x, u1.y, u1.z, u1.w};
#pragma unroll
                for (int q = 0; q < 8; ++q) {
                    int kq = kk + sk0 + q * 2;
                    float e0 = bfu2f(uu[q] & 0xffffu) * s_sc[kq] + s_sh[kq];
                    float e1 = bfhi2f(uu[q]) * s_sc[kq + 1] + s_sh[kq + 1];
                    e0 = (e0 >= 0.f) ? e0 : ALPHA * e0;
                    e1 = (e1 >= 0.f) ? e1 : ALPHA * e1;
                    tmp[q * 2 + 0] = f2bf(e0);
                    tmp[q * 2 + 1] = f2bf(e1);
                }
            }
        }
        *(uint4*)&As[srow * LDA + sk0] = *(uint4*)&tmp[0];
        *(uint4*)&As[srow * LDA + sk0 + 8] = *(uint4*)&tmp[8];

        uint4 ub = *(const uint4*)(BT + (size_t)(bcol + sbc) * K + kk + sbk);
        *(uint4*)&Bs[sbc * LDA + sbk] = ub;

        __syncthreads();

        short8 af[4], bfv[2];
#pragma unroll
        for (int mi = 0; mi < 4; ++mi)
            af[mi] = *(const short8*)&As[(wr * 64 + mi * 16 + fr) * LDA + fk];
#pragma unroll
        for (int ni = 0; ni < 2; ++ni)
            bfv[ni] = *(const short8*)&Bs[(wc * 32 + ni * 16 + fr) * LDA + fk];
#pragma unroll
        for (int mi = 0; mi < 4; ++mi)
#pragma unroll
            for (int ni = 0; ni < 2; ++ni)
                acc[mi][ni] = __builtin_amdgcn_mfma_f32_16x16x32_bf16(af[mi], bfv[ni], acc[mi][ni], 0, 0, 0);

        __syncthreads();
    }

    float bv[2];
#pragma unroll
    for (int ni = 0; ni < 2; ++ni) bv[ni] = bias[bcol + wc * 32 + ni * 16 + fr];

    if constexpr (OUT == 1) {
        float* outf = (float*)Cp;
#pragma unroll
        for (int mi = 0; mi < 4; ++mi)
#pragma unroll
            for (int r = 0; r < 4; ++r) {
                int row = brow + wr * 64 + mi * 16 + fq * 4 + r;
                if (row < NN) {
#pragma unroll
                    for (int ni = 0; ni < 2; ++ni) {
                        int c = bcol + wc * 32 + ni * 16 + fr;
                        outf[(size_t)row * NOUT + c] = acc[mi][ni][r] + bv[ni];
                    }
                }
            }
    } else {
        ushort* outb = (ushort*)Cp;
#pragma unroll
        for (int mi = 0; mi < 4; ++mi)
#pragma unroll
            for (int r = 0; r < 4; ++r) {
                int row = brow + wr * 64 + mi * 16 + fq * 4 + r;
                if (row < NN) {
#pragma unroll
                    for (int ni = 0; ni < 2; ++ni) {
                        int c = bcol + wc * 32 + ni * 16 + fr;
                        outb[(size_t)row * NOUT + c] = f2bf(acc[mi][ni][r] + bv[ni]);
                    }
                }
            }
    }
}

// ================= BN statistics =================
template <int M>
__global__ __launch_bounds__(256) void k_bnpart(const ushort* __restrict__ X, float* __restrict__ partials) {
    constexpr int FG = M / 4, RP = 256 / FG;
    __shared__ float rs[RP * M];
    __shared__ float rq[RP * M];
    int fg = threadIdx.x % FG, r0 = threadIdx.x / FG;
    float s0 = 0, s1 = 0, s2 = 0, s3 = 0, q0 = 0, q1 = 0, q2 = 0, q3 = 0;
    for (int n = blockIdx.x * RP + r0; n < NN; n += GBN * RP) {
        uint2 u = ((const uint2*)X)[(size_t)n * FG + fg];
        float v0 = bfu2f(u.x & 0xffffu), v1 = bfhi2f(u.x);
        float v2 = bfu2f(u.y & 0xffffu), v3 = bfhi2f(u.y);
        s0 += v0; q0 += v0 * v0;
        s1 += v1; q1 += v1 * v1;
        s2 += v2; q2 += v2 * v2;
        s3 += v3; q3 += v3 * v3;
    }
    int f0 = fg * 4;
    rs[r0 * M + f0 + 0] = s0; rq[r0 * M + f0 + 0] = q0;
    rs[r0 * M + f0 + 1] = s1; rq[r0 * M + f0 + 1] = q1;
    rs[r0 * M + f0 + 2] = s2; rq[r0 * M + f0 + 2] = q2;
    rs[r0 * M + f0 + 3] = s3; rq[r0 * M + f0 + 3] = q3;
    __syncthreads();
    for (int h = RP / 2; h; h >>= 1) {
        if (r0 < h) {
#pragma unroll
            for (int j = 0; j < 4; ++j) {
                rs[r0 * M + f0 + j] += rs[(r0 + h) * M + f0 + j];
                rq[r0 * M + f0 + j] += rq[(r0 + h) * M + f0 + j];
            }
        }
        __syncthreads();
    }
    if (threadIdx.x < M) {
        partials[(size_t)blockIdx.x * 2 * M + threadIdx.x] = rs[threadIdx.x];
        partials[(size_t)blockIdx.x * 2 * M + M + threadIdx.x] = rq[threadIdx.x];
    }
}

template <int M>
__global__ void k_bnred(const float* __restrict__ partials, const float* __restrict__ g,
                        const float* __restrict__ be, float* __restrict__ scale,
                        float* __restrict__ shift) {
    int f = threadIdx.x;
    if (f < M) {
        float s = 0.f, q = 0.f;
        for (int b = 0; b < GBN; ++b) {
            s += partials[(size_t)b * 2 * M + f];
            q += partials[(size_t)b * 2 * M + M + f];
        }
        float mu = s * (1.f / NN);
        float var = q * (1.f / NN) - mu * mu;
        float r = rsqrtf(var + EPS_BN);
        float sc = g[f] * r;
        scale[f] = sc;
        shift[f] = be[f] - mu * sc;
    }
}

// ================= launch =================
extern "C" void kernel_launch(void* const* d_in, const int* in_sizes, int n_in,
                              void* d_out, int out_size, void* d_ws, size_t ws_size,
                              hipStream_t stream) {
    const float* emb = (const float*)d_in[0];
    const int* eidx  = (const int*)d_in[1];
    const float* W1  = (const float*)d_in[2];
    const float* b1  = (const float*)d_in[3];
    const float* g1  = (const float*)d_in[4];
    const float* be1 = (const float*)d_in[5];
    const float* W2  = (const float*)d_in[6];
    const float* b2  = (const float*)d_in[7];
    const float* g2  = (const float*)d_in[8];
    const float* be2 = (const float*)d_in[9];
    const float* Wf  = (const float*)d_in[10];
    const float* bf  = (const float*)d_in[11];
    float* out = (float*)d_out;
    const int* srcv = eidx;
    const int* dstv = eidx + NE;

    char* w = (char*)d_ws;
    auto alloc = [&](size_t bytes) {
        char* p = w;
        w += (bytes + 255) / 256 * 256;
        return p;
    };
    int* cnt    = (int*)alloc((size_t)NN * 4);
    int* indptr = (int*)alloc((size_t)NN * 4);
    int* bcnt   = (int*)alloc((size_t)NBUCK * GA * 4);
    int* gcur   = (int*)alloc((size_t)NBUCK * GA * 4);
    int* bbase  = (int*)alloc((size_t)(NBUCK + 1) * 4);
    int* colb   = (int*)alloc((size_t)NE * 4);
    uint* bpair = (uint*)alloc((size_t)NE * 4);
    float* dinv = (float*)alloc((size_t)NN * 4);
    float* partials = (float*)alloc((size_t)GBN * 512 * 4);
    float* sc1 = (float*)alloc(128 * 4);
    float* sh1 = (float*)alloc(128 * 4);
    float* sc2 = (float*)alloc(256 * 4);
    float* sh2 = (float*)alloc(256 * 4);
    ushort* w1t = (ushort*)alloc((size_t)128 * 64 * 2);
    ushort* w2t = (ushort*)alloc((size_t)256 * 128 * 2);
    ushort* wft = (ushort*)alloc((size_t)256 * 256 * 2);
    // slabA: embs(12.8MB) -> H1(25.6MB) -> agg2(25.6MB)
    ushort* slabA = (ushort*)alloc((size_t)NN * 128 * 2);
    // slabB: aggE(12.8MB) -> x2s(25.6MB)
    ushort* slabB = (ushort*)alloc((size_t)NN * 128 * 2);
    // slabC: H2 (51.2MB)
    ushort* H2 = (ushort*)alloc((size_t)NN * 256 * 2);

    ushort* embs = slabA;
    ushort* aggE = slabB;
    ushort* H1   = slabA;
    ushort* x2s  = slabB;
    ushort* agg2 = slabA;

    // ---- CSR build (bucketed, low write-amplification) ----
    k_bhist<<<GA, 256, 0, stream>>>(dstv, bcnt);
    k_bscan<<<1, 1024, 0, stream>>>(bcnt, gcur, bbase);
    k_bscatter<<<GA, 256, 0, stream>>>(srcv, dstv, gcur, bpair);
    k_bcsr<<<NBUCK, 256, 0, stream>>>(bpair, bbase, colb, cnt, indptr);
    k_dinv<<<NBLK, 256, 0, stream>>>(cnt, dinv);

    // ---- weights -> bf16 transposed ----
    k_wtrans<<<(64 * 128 + 255) / 256, 256, 0, stream>>>(W1, w1t, 64, 128);
    k_wtrans<<<(128 * 256 + 255) / 256, 256, 0, stream>>>(W2, w2t, 128, 256);
    k_wtrans<<<(256 * 256 + 255) / 256, 256, 0, stream>>>(Wf, wft, 256, 256);

    constexpr int GX = (NN + 127) / 128;   // 782

    // ---- layer 1: aggregate input (64-wide) first, then GEMM ----
    k_semb<<<(NN * 16 + 255) / 256, 256, 0, stream>>>(emb, dinv, (uint2*)embs);
    k_agg<64><<<NN, 64, 0, stream>>>(embs, indptr, cnt, colb, dinv, aggE);
    k_mgemm<64, 128, 2, 2><<<dim3(GX, 2), 256, 0, stream>>>(aggE, w1t, H1, nullptr, nullptr, b1);
    k_bnpart<128><<<GBN, 256, 0, stream>>>(H1, partials);
    k_bnred<128><<<1, 256, 0, stream>>>(partials, g1, be1, sc1, sh1);

    // ---- layer 2: elementwise BN+leaky+dinv, aggregate (128-wide), GEMM ----
    k_x2s<<<(NN * 16 + 255) / 256, 256, 0, stream>>>(H1, sc1, sh1, dinv, x2s);
    k_agg<128><<<NN, 64, 0, stream>>>(x2s, indptr, cnt, colb, dinv, agg2);
    k_mgemm<128, 256, 2, 2><<<dim3(GX, 4), 256, 0, stream>>>(agg2, w2t, H2, nullptr, nullptr, b2);
    k_bnpart<256><<<GBN, 256, 0, stream>>>(H2, partials);
    k_bnred<256><<<1, 256, 0, stream>>>(partials, g2, be2, sc2, sh2);

    // ---- final linear -> fp32 d_out ----
    k_mgemm<256, 256, 1, 1><<<dim3(GX, 4), 256, 0, stream>>>(H2, wft, out, sc2, sh2, bf);
}

// Round 5
// 382.247 us; speedup vs baseline: 2.7124x; 1.1305x over previous
//
#include <hip/hip_runtime.h>

#define NN 100000
#define NE 1600000
constexpr float EPS_BN = 1e-5f;
constexpr float ALPHA = 0.01f;
constexpr int GBN = 128;                    // bnpart grid
constexpr int NBUCK = (NN + 127) / 128;     // 782 buckets of 128 nodes
constexpr int GA = 128;                     // bucket-pass blocks
constexpr int EPB = NE / GA;                // 12500 edges/block (exact)

typedef __attribute__((ext_vector_type(8))) short short8;
typedef __attribute__((ext_vector_type(4))) float f32x4;

// ---- bf16 helpers ----
__device__ __forceinline__ float bfu2f(uint lo16) {
    union { uint i; float f; } v; v.i = lo16 << 16; return v.f;
}
__device__ __forceinline__ float bfhi2f(uint u) {
    union { uint i; float f; } v; v.i = u & 0xffff0000u; return v.f;
}
__device__ __forceinline__ ushort f2bf(float f) {     // RNE
    union { float f; uint i; } v; v.f = f;
    return (ushort)((v.i + 0x7fffu + ((v.i >> 16) & 1u)) >> 16);
}

// ================= bucketed CSR build =================
// layout: bcnt/gcur are [block][bucket] so k_bscan reads/writes coalesced
__global__ __launch_bounds__(256) void k_bhist(const int* __restrict__ dstv, int* __restrict__ bcnt) {
    __shared__ int hist[NBUCK];
    for (int i = threadIdx.x; i < NBUCK; i += 256) hist[i] = 0;
    __syncthreads();
    int base = blockIdx.x * EPB;
    for (int i = threadIdx.x; i < EPB; i += 256)
        atomicAdd(&hist[dstv[base + i] >> 7], 1);
    __syncthreads();
    for (int i = threadIdx.x; i < NBUCK; i += 256)
        bcnt[blockIdx.x * NBUCK + i] = hist[i];
}

__global__ __launch_bounds__(1024) void k_bscan(const int* __restrict__ bcnt,
                                                int* __restrict__ gcur, int* __restrict__ bbase) {
    __shared__ int tot[1024];
    int b = threadIdx.x;
    int t = 0;
    if (b < NBUCK)
        for (int k = 0; k < GA; ++k) t += bcnt[k * NBUCK + b];
    tot[b] = t;
    __syncthreads();
    for (int off = 1; off < 1024; off <<= 1) {
        int u = (b >= off) ? tot[b - off] : 0;
        __syncthreads();
        tot[b] += u;
        __syncthreads();
    }
    int ex = tot[b] - t;   // exclusive
    if (b < NBUCK) {
        bbase[b] = ex;
        int cur = ex;
        for (int k = 0; k < GA; ++k) { gcur[k * NBUCK + b] = cur; cur += bcnt[k * NBUCK + b]; }
    }
    if (b == 0) bbase[NBUCK] = NE;
}

__global__ __launch_bounds__(256) void k_bscatter(const int* __restrict__ srcv, const int* __restrict__ dstv,
                                                  const int* __restrict__ gcur, uint* __restrict__ bpair) {
    __shared__ int lcur[NBUCK];
    for (int i = threadIdx.x; i < NBUCK; i += 256) lcur[i] = gcur[blockIdx.x * NBUCK + i];
    __syncthreads();
    int base = blockIdx.x * EPB;
    for (int i = threadIdx.x; i < EPB; i += 256) {
        int d = dstv[base + i], s = srcv[base + i];
        int slot = atomicAdd(&lcur[d >> 7], 1);
        bpair[slot] = ((uint)(d & 127) << 17) | (uint)s;
    }
}

// per-bucket -> CSR col + degrees + indptr + dinv (fused)
__global__ __launch_bounds__(256) void k_bcsr(const uint* __restrict__ bpair, const int* __restrict__ bbase,
                                              int* __restrict__ col, int* __restrict__ cnt,
                                              int* __restrict__ indptr, float* __restrict__ dinv) {
    __shared__ int h[128];
    __shared__ int off[128];
    int b = blockIdx.x, t = threadIdx.x;
    int p0 = bbase[b], p1 = bbase[b + 1];
    if (t < 128) h[t] = 0;
    __syncthreads();
    for (int i = p0 + t; i < p1; i += 256)
        atomicAdd(&h[bpair[i] >> 17], 1);
    __syncthreads();
    if (t < 128) off[t] = h[t];
    __syncthreads();
    for (int o = 1; o < 128; o <<= 1) {
        int u = 0;
        if (t < 128 && t >= o) u = off[t - o];
        __syncthreads();
        if (t < 128) off[t] += u;
        __syncthreads();
    }
    if (t < 128) {
        int st = p0 + off[t] - h[t];
        int node = b * 128 + t;
        if (node < NN) {
            indptr[node] = st;
            cnt[node] = h[t];
            dinv[node] = rsqrtf((float)(h[t] + 1));   // +1 self loop
        }
        off[t] = st;
    }
    __syncthreads();
    for (int i = p0 + t; i < p1; i += 256) {
        uint u = bpair[i];
        int slot = atomicAdd(&off[u >> 17], 1);
        col[slot] = (int)(u & 0x1FFFFu);
    }
}

// ================= all weights -> bf16 transposed [M][K], one launch =================
__global__ void k_wtrans_all(const float* __restrict__ W1, const float* __restrict__ W2,
                             const float* __restrict__ Wf, ushort* __restrict__ w1t,
                             ushort* __restrict__ w2t, ushort* __restrict__ wft) {
    int i = blockIdx.x * 256 + threadIdx.x;
    if (i < 8192) {                    // W1: 64x128 -> [128][64]
        int m = i / 64, k = i % 64;
        w1t[i] = f2bf(W1[(size_t)k * 128 + m]);
    } else if (i < 8192 + 32768) {     // W2: 128x256 -> [256][128]
        int j = i - 8192;
        int m = j / 128, k = j % 128;
        w2t[j] = f2bf(W2[(size_t)k * 256 + m]);
    } else if (i < 8192 + 32768 + 65536) {   // Wf: 256x256 -> [256][256]
        int j = i - 8192 - 32768;
        int m = j / 256, k = j % 256;
        wft[j] = f2bf(Wf[(size_t)k * 256 + m]);
    }
}

// ================= elementwise pre-passes =================
__global__ __launch_bounds__(256) void k_semb(const float* __restrict__ emb, const float* __restrict__ dinv,
                                              uint2* __restrict__ embs) {
    int i = blockIdx.x * 256 + threadIdx.x;   // uint2 index: 4 feats
    if (i >= NN * 16) return;
    int row = i >> 4;
    float dn = dinv[row];
    float4 f = ((const float4*)emb)[i];
    uint2 o;
    o.x = (uint)f2bf(f.x * dn) | ((uint)f2bf(f.y * dn) << 16);
    o.y = (uint)f2bf(f.z * dn) | ((uint)f2bf(f.w * dn) << 16);
    embs[i] = o;
}

__global__ __launch_bounds__(256) void k_x2s(const ushort* __restrict__ H1, const float* __restrict__ sc,
                                             const float* __restrict__ sh, const float* __restrict__ dinv,
                                             ushort* __restrict__ x2s) {
    int i = blockIdx.x * 256 + threadIdx.x;   // uint4 index: 8 feats
    if (i >= NN * 16) return;
    int row = i >> 4, f0 = (i & 15) * 8;
    float dn = dinv[row];
    uint4 u = ((const uint4*)H1)[i];
    uint uu[4] = {u.x, u.y, u.z, u.w};
    uint oo[4];
#pragma unroll
    for (int q = 0; q < 4; ++q) {
        int f = f0 + q * 2;
        float e0 = bfu2f(uu[q] & 0xffffu) * sc[f] + sh[f];
        float e1 = bfhi2f(uu[q]) * sc[f + 1] + sh[f + 1];
        e0 = ((e0 >= 0.f) ? e0 : ALPHA * e0) * dn;
        e1 = ((e1 >= 0.f) ? e1 : ALPHA * e1) * dn;
        oo[q] = (uint)f2bf(e0) | ((uint)f2bf(e1) << 16);
    }
    uint4 o; o.x = oo[0]; o.y = oo[1]; o.z = oo[2]; o.w = oo[3];
    ((uint4*)x2s)[i] = o;
}

// ================= CSR gather aggregation (bf16, fp32 accum) =================
template <int W>
__global__ __launch_bounds__(64) void k_agg(const ushort* __restrict__ X, const int* __restrict__ indptr,
                                            const int* __restrict__ cnt, const int* __restrict__ col,
                                            const float* __restrict__ dinv, ushort* __restrict__ out) {
    int n = blockIdx.x, t = threadIdx.x;
    __shared__ int sc[64];
    int start = indptr[n], c = cnt[n];
    if constexpr (W == 64) {
        float a0 = bfu2f(X[(size_t)n * 64 + t]);
        for (int base = 0; base < c; base += 64) {
            int m = min(64, c - base);
            if (t < m) sc[t] = col[start + base + t];
            __syncthreads();
#pragma unroll 4
            for (int j = 0; j < m; ++j)
                a0 += bfu2f(X[(size_t)sc[j] * 64 + t]);
            __syncthreads();
        }
        out[(size_t)n * 64 + t] = f2bf(a0 * dinv[n]);
    } else {   // W == 128
        const uint* Xu = (const uint*)X;
        uint u = Xu[(size_t)n * 64 + t];
        float a0 = bfu2f(u & 0xffffu), a1 = bfhi2f(u);
        for (int base = 0; base < c; base += 64) {
            int m = min(64, c - base);
            if (t < m) sc[t] = col[start + base + t];
            __syncthreads();
#pragma unroll 4
            for (int j = 0; j < m; ++j) {
                uint v = Xu[(size_t)sc[j] * 64 + t];
                a0 += bfu2f(v & 0xffffu); a1 += bfhi2f(v);
            }
            __syncthreads();
        }
        float dn = dinv[n];
        ((uint*)out)[(size_t)n * 64 + t] = (uint)f2bf(a0 * dn) | ((uint)f2bf(a1 * dn) << 16);
    }
}

// ================= MFMA bf16 GEMM, full-width column tile (A read once) =================
// AT 1: A bf16, apply leaky(A*sc+sh) on stage     AT 2: A bf16 raw
// OUT 1: C = fp32( acc + bias[col] )              OUT 2: C = bf16( acc + bias[col] )
// B pre-transposed bf16 [NOUT][K]. Grid: (ceil(NN/128)), 256 threads, 2x2 waves.
template <int K, int NOUT, int AT, int OUT>
__global__ __launch_bounds__(256) void k_mgemm(
        const void* __restrict__ Ap, const ushort* __restrict__ BT, void* __restrict__ Cp,
        const float* __restrict__ scale, const float* __restrict__ shift,
        const float* __restrict__ bias) {
    constexpr int BM = 128, BK = 32, LDA = 40;
    constexpr int WN = NOUT / 2;          // wave col width: 64 or 128
    constexpr int NF = WN / 16;           // col frags/wave: 4 or 8
    __shared__ ushort As[BM * LDA];
    __shared__ ushort Bs[NOUT * LDA];
    __shared__ float s_sc[K];
    __shared__ float s_sh[K];

    int tid = threadIdx.x;
    int brow = blockIdx.x * BM;
    if constexpr (AT == 1) {
        for (int i = tid; i < K; i += 256) { s_sc[i] = scale[i]; s_sh[i] = shift[i]; }
        __syncthreads();
    }

    int lane = tid & 63, wid = tid >> 6;
    int wr = wid >> 1, wc = wid & 1;      // wave tile: 64 rows x WN cols
    int fr = lane & 15, fq = lane >> 4;
    int fk = fq * 8;

    f32x4 acc[4][NF];
#pragma unroll
    for (int mi = 0; mi < 4; ++mi)
#pragma unroll
        for (int ni = 0; ni < NF; ++ni) acc[mi][ni] = (f32x4){0.f, 0.f, 0.f, 0.f};

    const int srow = tid >> 1, sk0 = (tid & 1) * 16;   // A: 16 bf16/thread
    const int grow = brow + srow;
    const bool aok = grow < NN;

    for (int kk = 0; kk < K; kk += BK) {
        __align__(16) ushort tmp[16];
#pragma unroll
        for (int j = 0; j < 16; ++j) tmp[j] = 0;
        if (aok) {
            const ushort* ap = (const ushort*)Ap + (size_t)grow * K + kk + sk0;
            if constexpr (AT == 2) {
                *(uint4*)&tmp[0] = *(const uint4*)ap;
                *(uint4*)&tmp[8] = *(const uint4*)(ap + 8);
            } else {
                uint4 u0 = *(const uint4*)ap;
                uint4 u1 = *(const uint4*)(ap + 8);
                uint uu[8] = {u0.x, u0.y, u0.z, u0.w, u1.x, u1.y, u1.z, u1.w};
#pragma unroll
                for (int q = 0; q < 8; ++q) {
                    int kq = kk + sk0 + q * 2;
                    float e0 = bfu2f(uu[q] & 0xffffu) * s_sc[kq] + s_sh[kq];
                    float e1 = bfhi2f(uu[q]) * s_sc[kq + 1] + s_sh[kq + 1];
                    e0 = (e0 >= 0.f) ? e0 : ALPHA * e0;
                    e1 = (e1 >= 0.f) ? e1 : ALPHA * e1;
                    tmp[q * 2 + 0] = f2bf(e0);
                    tmp[q * 2 + 1] = f2bf(e1);
                }
            }
        }
        *(uint4*)&As[srow * LDA + sk0] = *(uint4*)&tmp[0];
        *(uint4*)&As[srow * LDA + sk0 + 8] = *(uint4*)&tmp[8];

        // B: NOUT*32 bf16 per K-step, 8 per thread per iter
#pragma unroll
        for (int it = 0; it < NOUT * BK / (256 * 8); ++it) {
            int idx = tid + it * 256;
            int bro = idx >> 2, bk = (idx & 3) * 8;
            *(uint4*)&Bs[bro * LDA + bk] = *(const uint4*)(BT + (size_t)bro * K + kk + bk);
        }

        __syncthreads();

        short8 af[4], bfv[NF];
#pragma unroll
        for (int mi = 0; mi < 4; ++mi)
            af[mi] = *(const short8*)&As[(wr * 64 + mi * 16 + fr) * LDA + fk];
#pragma unroll
        for (int ni = 0; ni < NF; ++ni)
            bfv[ni] = *(const short8*)&Bs[(wc * WN + ni * 16 + fr) * LDA + fk];
#pragma unroll
        for (int mi = 0; mi < 4; ++mi)
#pragma unroll
            for (int ni = 0; ni < NF; ++ni)
                acc[mi][ni] = __builtin_amdgcn_mfma_f32_16x16x32_bf16(af[mi], bfv[ni], acc[mi][ni], 0, 0, 0);

        __syncthreads();
    }

    float bv[NF];
#pragma unroll
    for (int ni = 0; ni < NF; ++ni) bv[ni] = bias[wc * WN + ni * 16 + fr];

    if constexpr (OUT == 1) {
        float* outf = (float*)Cp;
#pragma unroll
        for (int mi = 0; mi < 4; ++mi)
#pragma unroll
            for (int r = 0; r < 4; ++r) {
                int row = brow + wr * 64 + mi * 16 + fq * 4 + r;
                if (row < NN) {
#pragma unroll
                    for (int ni = 0; ni < NF; ++ni) {
                        int c = wc * WN + ni * 16 + fr;
                        outf[(size_t)row * NOUT + c] = acc[mi][ni][r] + bv[ni];
                    }
                }
            }
    } else {
        ushort* outb = (ushort*)Cp;
#pragma unroll
        for (int mi = 0; mi < 4; ++mi)
#pragma unroll
            for (int r = 0; r < 4; ++r) {
                int row = brow + wr * 64 + mi * 16 + fq * 4 + r;
                if (row < NN) {
#pragma unroll
                    for (int ni = 0; ni < NF; ++ni) {
                        int c = wc * WN + ni * 16 + fr;
                        outb[(size_t)row * NOUT + c] = f2bf(acc[mi][ni][r] + bv[ni]);
                    }
                }
            }
    }
}

// ================= BN statistics (uint4 loads, atomic-free) =================
template <int M>
__global__ __launch_bounds__(256) void k_bnpart(const ushort* __restrict__ X, float* __restrict__ partials) {
    constexpr int FG = M / 8, RP = 256 / FG;   // 8 feats/thread
    __shared__ float rs[RP * M];
    __shared__ float rq[RP * M];
    int fg = threadIdx.x % FG, r0 = threadIdx.x / FG;
    float s[8] = {0, 0, 0, 0, 0, 0, 0, 0}, q[8] = {0, 0, 0, 0, 0, 0, 0, 0};
    for (int n = blockIdx.x * RP + r0; n < NN; n += GBN * RP) {
        uint4 u = ((const uint4*)X)[(size_t)n * FG + fg];
        uint uu[4] = {u.x, u.y, u.z, u.w};
#pragma unroll
        for (int p = 0; p < 4; ++p) {
            float v0 = bfu2f(uu[p] & 0xffffu), v1 = bfhi2f(uu[p]);
            s[p * 2] += v0; q[p * 2] += v0 * v0;
            s[p * 2 + 1] += v1; q[p * 2 + 1] += v1 * v1;
        }
    }
    int f0 = fg * 8;
#pragma unroll
    for (int j = 0; j < 8; ++j) {
        rs[r0 * M + f0 + j] = s[j];
        rq[r0 * M + f0 + j] = q[j];
    }
    __syncthreads();
    for (int h = RP / 2; h; h >>= 1) {
        if (r0 < h) {
#pragma unroll
            for (int j = 0; j < 8; ++j) {
                rs[r0 * M + f0 + j] += rs[(r0 + h) * M + f0 + j];
                rq[r0 * M + f0 + j] += rq[(r0 + h) * M + f0 + j];
            }
        }
        __syncthreads();
    }
    if (threadIdx.x < M) {
        partials[(size_t)blockIdx.x * 2 * M + threadIdx.x] = rs[threadIdx.x];
        partials[(size_t)blockIdx.x * 2 * M + M + threadIdx.x] = rq[threadIdx.x];
    }
}

template <int M>
__global__ void k_bnred(const float* __restrict__ partials, const float* __restrict__ g,
                        const float* __restrict__ be, float* __restrict__ scale,
                        float* __restrict__ shift) {
    int f = threadIdx.x;
    if (f < M) {
        float s = 0.f, q = 0.f;
        for (int b = 0; b < GBN; ++b) {
            s += partials[(size_t)b * 2 * M + f];
            q += partials[(size_t)b * 2 * M + M + f];
        }
        float mu = s * (1.f / NN);
        float var = q * (1.f / NN) - mu * mu;
        float r = rsqrtf(var + EPS_BN);
        float sc = g[f] * r;
        scale[f] = sc;
        shift[f] = be[f] - mu * sc;
    }
}

// ================= launch =================
extern "C" void kernel_launch(void* const* d_in, const int* in_sizes, int n_in,
                              void* d_out, int out_size, void* d_ws, size_t ws_size,
                              hipStream_t stream) {
    const float* emb = (const float*)d_in[0];
    const int* eidx  = (const int*)d_in[1];
    const float* W1  = (const float*)d_in[2];
    const float* b1  = (const float*)d_in[3];
    const float* g1  = (const float*)d_in[4];
    const float* be1 = (const float*)d_in[5];
    const float* W2  = (const float*)d_in[6];
    const float* b2  = (const float*)d_in[7];
    const float* g2  = (const float*)d_in[8];
    const float* be2 = (const float*)d_in[9];
    const float* Wf  = (const float*)d_in[10];
    const float* bf  = (const float*)d_in[11];
    float* out = (float*)d_out;
    const int* srcv = eidx;
    const int* dstv = eidx + NE;

    char* w = (char*)d_ws;
    auto alloc = [&](size_t bytes) {
        char* p = w;
        w += (bytes + 255) / 256 * 256;
        return p;
    };
    int* cnt    = (int*)alloc((size_t)NN * 4);
    int* indptr = (int*)alloc((size_t)NN * 4);
    int* bcnt   = (int*)alloc((size_t)NBUCK * GA * 4);
    int* gcur   = (int*)alloc((size_t)NBUCK * GA * 4);
    int* bbase  = (int*)alloc((size_t)(NBUCK + 1) * 4);
    int* colb   = (int*)alloc((size_t)NE * 4);
    uint* bpair = (uint*)alloc((size_t)NE * 4);
    float* dinv = (float*)alloc((size_t)NN * 4);
    float* partials = (float*)alloc((size_t)GBN * 512 * 4);
    float* sc1 = (float*)alloc(128 * 4);
    float* sh1 = (float*)alloc(128 * 4);
    float* sc2 = (float*)alloc(256 * 4);
    float* sh2 = (float*)alloc(256 * 4);
    ushort* w1t = (ushort*)alloc((size_t)128 * 64 * 2);
    ushort* w2t = (ushort*)alloc((size_t)256 * 128 * 2);
    ushort* wft = (ushort*)alloc((size_t)256 * 256 * 2);
    ushort* slabA = (ushort*)alloc((size_t)NN * 128 * 2);   // embs -> H1 -> agg2
    ushort* slabB = (ushort*)alloc((size_t)NN * 128 * 2);   // aggE -> x2s
    ushort* H2 = (ushort*)alloc((size_t)NN * 256 * 2);

    ushort* embs = slabA;
    ushort* aggE = slabB;
    ushort* H1   = slabA;
    ushort* x2s  = slabB;
    ushort* agg2 = slabA;

    // ---- CSR build ----
    k_bhist<<<GA, 256, 0, stream>>>(dstv, bcnt);
    k_bscan<<<1, 1024, 0, stream>>>(bcnt, gcur, bbase);
    k_bscatter<<<GA, 256, 0, stream>>>(srcv, dstv, gcur, bpair);
    k_bcsr<<<NBUCK, 256, 0, stream>>>(bpair, bbase, colb, cnt, indptr, dinv);

    // ---- weights ----
    k_wtrans_all<<<(8192 + 32768 + 65536 + 255) / 256, 256, 0, stream>>>(W1, W2, Wf, w1t, w2t, wft);

    constexpr int GX = (NN + 127) / 128;   // 782

    // ---- layer 1 ----
    k_semb<<<(NN * 16 + 255) / 256, 256, 0, stream>>>(emb, dinv, (uint2*)embs);
    k_agg<64><<<NN, 64, 0, stream>>>(embs, indptr, cnt, colb, dinv, aggE);
    k_mgemm<64, 128, 2, 2><<<GX, 256, 0, stream>>>(aggE, w1t, H1, nullptr, nullptr, b1);
    k_bnpart<128><<<GBN, 256, 0, stream>>>(H1, partials);
    k_bnred<128><<<1, 256, 0, stream>>>(partials, g1, be1, sc1, sh1);

    // ---- layer 2 ----
    k_x2s<<<(NN * 16 + 255) / 256, 256, 0, stream>>>(H1, sc1, sh1, dinv, x2s);
    k_agg<128><<<NN, 64, 0, stream>>>(x2s, indptr, cnt, colb, dinv, agg2);
    k_mgemm<128, 256, 2, 2><<<GX, 256, 0, stream>>>(agg2, w2t, H2, nullptr, nullptr, b2);
    k_bnpart<256><<<GBN, 256, 0, stream>>>(H2, partials);
    k_bnred<256><<<1, 256, 0, stream>>>(partials, g2, be2, sc2, sh2);

    // ---- final linear -> fp32 d_out ----
    k_mgemm<256, 256, 1, 1><<<GX, 256, 0, stream>>>(H2, wft, out, sc2, sh2, bf);
}

// Round 6
// 364.350 us; speedup vs baseline: 2.8456x; 1.0491x over previous
//
#include <hip/hip_runtime.h>

#define NN 100000
#define NE 1600000
constexpr float EPS_BN = 1e-5f;
constexpr float ALPHA = 0.01f;
constexpr int GBN = 128;                    // bnpart grid
constexpr int NBUCK = (NN + 127) / 128;     // 782 buckets of 128 nodes
constexpr int GA = 128;                     // bucket-pass blocks
constexpr int EPB = NE / GA;                // 12500 edges/block (exact)

typedef __attribute__((ext_vector_type(8))) short short8;
typedef __attribute__((ext_vector_type(4))) float f32x4;

// ---- bf16 helpers ----
__device__ __forceinline__ float bfu2f(uint lo16) {
    union { uint i; float f; } v; v.i = lo16 << 16; return v.f;
}
__device__ __forceinline__ float bfhi2f(uint u) {
    union { uint i; float f; } v; v.i = u & 0xffff0000u; return v.f;
}
__device__ __forceinline__ ushort f2bf(float f) {     // RNE
    union { float f; uint i; } v; v.f = f;
    return (ushort)((v.i + 0x7fffu + ((v.i >> 16) & 1u)) >> 16);
}

// ================= bucketed CSR build =================
__global__ __launch_bounds__(256) void k_bhist(const int* __restrict__ dstv, int* __restrict__ bcnt) {
    __shared__ int hist[NBUCK];
    for (int i = threadIdx.x; i < NBUCK; i += 256) hist[i] = 0;
    __syncthreads();
    int base = blockIdx.x * EPB;
    for (int i = threadIdx.x; i < EPB; i += 256)
        atomicAdd(&hist[dstv[base + i] >> 7], 1);
    __syncthreads();
    for (int i = threadIdx.x; i < NBUCK; i += 256)
        bcnt[blockIdx.x * NBUCK + i] = hist[i];
}

__global__ __launch_bounds__(1024) void k_bscan(const int* __restrict__ bcnt,
                                                int* __restrict__ gcur, int* __restrict__ bbase) {
    __shared__ int tot[1024];
    int b = threadIdx.x;
    int t = 0;
    if (b < NBUCK)
        for (int k = 0; k < GA; ++k) t += bcnt[k * NBUCK + b];
    tot[b] = t;
    __syncthreads();
    for (int off = 1; off < 1024; off <<= 1) {
        int u = (b >= off) ? tot[b - off] : 0;
        __syncthreads();
        tot[b] += u;
        __syncthreads();
    }
    int ex = tot[b] - t;   // exclusive
    if (b < NBUCK) {
        bbase[b] = ex;
        int cur = ex;
        for (int k = 0; k < GA; ++k) { gcur[k * NBUCK + b] = cur; cur += bcnt[k * NBUCK + b]; }
    }
    if (b == 0) bbase[NBUCK] = NE;
}

__global__ __launch_bounds__(256) void k_bscatter(const int* __restrict__ srcv, const int* __restrict__ dstv,
                                                  const int* __restrict__ gcur, uint* __restrict__ bpair) {
    __shared__ int lcur[NBUCK];
    for (int i = threadIdx.x; i < NBUCK; i += 256) lcur[i] = gcur[blockIdx.x * NBUCK + i];
    __syncthreads();
    int base = blockIdx.x * EPB;
    for (int i = threadIdx.x; i < EPB; i += 256) {
        int d = dstv[base + i], s = srcv[base + i];
        int slot = atomicAdd(&lcur[d >> 7], 1);
        bpair[slot] = ((uint)(d & 127) << 17) | (uint)s;
    }
}

__global__ __launch_bounds__(256) void k_bcsr(const uint* __restrict__ bpair, const int* __restrict__ bbase,
                                              int* __restrict__ col, int* __restrict__ cnt,
                                              int* __restrict__ indptr, float* __restrict__ dinv) {
    __shared__ int h[128];
    __shared__ int off[128];
    int b = blockIdx.x, t = threadIdx.x;
    int p0 = bbase[b], p1 = bbase[b + 1];
    if (t < 128) h[t] = 0;
    __syncthreads();
    for (int i = p0 + t; i < p1; i += 256)
        atomicAdd(&h[bpair[i] >> 17], 1);
    __syncthreads();
    if (t < 128) off[t] = h[t];
    __syncthreads();
    for (int o = 1; o < 128; o <<= 1) {
        int u = 0;
        if (t < 128 && t >= o) u = off[t - o];
        __syncthreads();
        if (t < 128) off[t] += u;
        __syncthreads();
    }
    if (t < 128) {
        int st = p0 + off[t] - h[t];
        int node = b * 128 + t;
        if (node < NN) {
            indptr[node] = st;
            cnt[node] = h[t];
            dinv[node] = rsqrtf((float)(h[t] + 1));   // +1 self loop
        }
        off[t] = st;
    }
    __syncthreads();
    for (int i = p0 + t; i < p1; i += 256) {
        uint u = bpair[i];
        int slot = atomicAdd(&off[u >> 17], 1);
        col[slot] = (int)(u & 0x1FFFFu);
    }
}

// ================= all weights -> bf16 transposed [M][K], one launch =================
__global__ void k_wtrans_all(const float* __restrict__ W1, const float* __restrict__ W2,
                             const float* __restrict__ Wf, ushort* __restrict__ w1t,
                             ushort* __restrict__ w2t, ushort* __restrict__ wft) {
    int i = blockIdx.x * 256 + threadIdx.x;
    if (i < 8192) {                    // W1: 64x128 -> [128][64]
        int m = i / 64, k = i % 64;
        w1t[i] = f2bf(W1[(size_t)k * 128 + m]);
    } else if (i < 8192 + 32768) {     // W2: 128x256 -> [256][128]
        int j = i - 8192;
        int m = j / 128, k = j % 128;
        w2t[j] = f2bf(W2[(size_t)k * 256 + m]);
    } else if (i < 8192 + 32768 + 65536) {   // Wf: 256x256 -> [256][256]
        int j = i - 8192 - 32768;
        int m = j / 256, k = j % 256;
        wft[j] = f2bf(Wf[(size_t)k * 256 + m]);
    }
}

// ================= elementwise pre-passes =================
__global__ __launch_bounds__(256) void k_semb(const float* __restrict__ emb, const float* __restrict__ dinv,
                                              uint2* __restrict__ embs) {
    int i = blockIdx.x * 256 + threadIdx.x;   // uint2 index: 4 feats
    if (i >= NN * 16) return;
    int row = i >> 4;
    float dn = dinv[row];
    float4 f = ((const float4*)emb)[i];
    uint2 o;
    o.x = (uint)f2bf(f.x * dn) | ((uint)f2bf(f.y * dn) << 16);
    o.y = (uint)f2bf(f.z * dn) | ((uint)f2bf(f.w * dn) << 16);
    embs[i] = o;
}

__global__ __launch_bounds__(256) void k_x2s(const ushort* __restrict__ H1, const float* __restrict__ sc,
                                             const float* __restrict__ sh, const float* __restrict__ dinv,
                                             ushort* __restrict__ x2s) {
    int i = blockIdx.x * 256 + threadIdx.x;   // uint4 index: 8 feats
    if (i >= NN * 16) return;
    int row = i >> 4, f0 = (i & 15) * 8;
    float dn = dinv[row];
    uint4 u = ((const uint4*)H1)[i];
    uint uu[4] = {u.x, u.y, u.z, u.w};
    uint oo[4];
#pragma unroll
    for (int q = 0; q < 4; ++q) {
        int f = f0 + q * 2;
        float e0 = bfu2f(uu[q] & 0xffffu) * sc[f] + sh[f];
        float e1 = bfhi2f(uu[q]) * sc[f + 1] + sh[f + 1];
        e0 = ((e0 >= 0.f) ? e0 : ALPHA * e0) * dn;
        e1 = ((e1 >= 0.f) ? e1 : ALPHA * e1) * dn;
        oo[q] = (uint)f2bf(e0) | ((uint)f2bf(e1) << 16);
    }
    uint4 o; o.x = oo[0]; o.y = oo[1]; o.z = oo[2]; o.w = oo[3];
    ((uint4*)x2s)[i] = o;
}

// ================= CSR gather aggregation =================
// W=64: half-wave per src row (32 lanes x 4B), 2 srcs concurrent, shfl merge
__global__ __launch_bounds__(64) void k_agg64(const ushort* __restrict__ X, const int* __restrict__ indptr,
                                              const int* __restrict__ cnt, const int* __restrict__ col,
                                              const float* __restrict__ dinv, ushort* __restrict__ out) {
    int n = blockIdx.x, t = threadIdx.x;
    int t2 = t & 31, h = t >> 5;
    __shared__ int sc[64];
    int start = indptr[n], c = cnt[n];
    const uint* Xu = (const uint*)X;
    float a0 = 0.f, a1 = 0.f;
    if (h == 0) {
        uint u = Xu[(size_t)n * 32 + t2];
        a0 = bfu2f(u & 0xffffu); a1 = bfhi2f(u);
    }
    for (int base = 0; base < c; base += 64) {
        int m = min(64, c - base);
        if (t < m) sc[t] = col[start + base + t];
        __syncthreads();
#pragma unroll 2
        for (int j = h; j < m; j += 2) {
            uint v = Xu[(size_t)sc[j] * 32 + t2];
            a0 += bfu2f(v & 0xffffu); a1 += bfhi2f(v);
        }
        __syncthreads();
    }
    a0 += __shfl_xor(a0, 32);
    a1 += __shfl_xor(a1, 32);
    if (h == 0) {
        float dn = dinv[n];
        ((uint*)out)[(size_t)n * 32 + t2] = (uint)f2bf(a0 * dn) | ((uint)f2bf(a1 * dn) << 16);
    }
}

// W=128: full wave per src row (64 lanes x 4B), dual accumulator chains
__global__ __launch_bounds__(64) void k_agg128(const ushort* __restrict__ X, const int* __restrict__ indptr,
                                               const int* __restrict__ cnt, const int* __restrict__ col,
                                               const float* __restrict__ dinv, ushort* __restrict__ out) {
    int n = blockIdx.x, t = threadIdx.x;
    __shared__ int sc[64];
    int start = indptr[n], c = cnt[n];
    const uint* Xu = (const uint*)X;
    uint u = Xu[(size_t)n * 64 + t];
    float a0 = bfu2f(u & 0xffffu), a1 = bfhi2f(u);
    float b0 = 0.f, b1 = 0.f;
    for (int base = 0; base < c; base += 64) {
        int m = min(64, c - base);
        if (t < m) sc[t] = col[start + base + t];
        __syncthreads();
        int j = 0;
#pragma unroll 2
        for (; j + 2 <= m; j += 2) {
            uint v0 = Xu[(size_t)sc[j] * 64 + t];
            uint v1 = Xu[(size_t)sc[j + 1] * 64 + t];
            a0 += bfu2f(v0 & 0xffffu); a1 += bfhi2f(v0);
            b0 += bfu2f(v1 & 0xffffu); b1 += bfhi2f(v1);
        }
        if (j < m) {
            uint v = Xu[(size_t)sc[j] * 64 + t];
            a0 += bfu2f(v & 0xffffu); a1 += bfhi2f(v);
        }
        __syncthreads();
    }
    a0 += b0; a1 += b1;
    float dn = dinv[n];
    ((uint*)out)[(size_t)n * 64 + t] = (uint)f2bf(a0 * dn) | ((uint)f2bf(a1 * dn) << 16);
}

// ================= MFMA bf16 GEMM: BM=64, no B-LDS, dbuf A, 1 barrier/K-step =================
// AT 1: apply leaky(A*sc+sh) on stage   AT 2: A bf16 raw
// OUT 1: C = fp32(acc + bias[col])      OUT 2: C = bf16(acc + bias[col])
// B pre-transposed bf16 [NOUT][K] (L2/L1-resident, read direct).
template <int AT>
__device__ __forceinline__ uint4 xform8(uint4 u, int kbase, const float* s_sc, const float* s_sh) {
    if constexpr (AT == 1) {
        uint uu[4] = {u.x, u.y, u.z, u.w};
        uint oo[4];
#pragma unroll
        for (int q = 0; q < 4; ++q) {
            int kq = kbase + q * 2;
            float e0 = bfu2f(uu[q] & 0xffffu) * s_sc[kq] + s_sh[kq];
            float e1 = bfhi2f(uu[q]) * s_sc[kq + 1] + s_sh[kq + 1];
            e0 = (e0 >= 0.f) ? e0 : ALPHA * e0;
            e1 = (e1 >= 0.f) ? e1 : ALPHA * e1;
            oo[q] = (uint)f2bf(e0) | ((uint)f2bf(e1) << 16);
        }
        return make_uint4(oo[0], oo[1], oo[2], oo[3]);
    } else {
        return u;
    }
}

template <int K, int NOUT, int AT, int OUT>
__global__ __launch_bounds__(256) void k_mgemm(
        const void* __restrict__ Ap, const ushort* __restrict__ BT, void* __restrict__ Cp,
        const float* __restrict__ scale, const float* __restrict__ shift,
        const float* __restrict__ bias) {
    constexpr int BM = 64, BK = 32, LDA = 40;
    constexpr int WN = NOUT / 4;          // wave col width: 32 or 64
    constexpr int NF = WN / 16;           // col frags/wave: 2 or 4
    constexpr int NT = K / BK;
    __shared__ ushort As[2][BM * LDA];
    __shared__ float s_sc[K];
    __shared__ float s_sh[K];

    int tid = threadIdx.x;
    int brow = blockIdx.x * BM;
    int lane = tid & 63, wid = tid >> 6;
    int fr = lane & 15, fq = lane >> 4;
    int fk = fq * 8;

    const int srow = tid >> 2, sk0 = (tid & 3) * 8;   // A-stage: 8 bf16/thread
    const int grow = brow + srow;
    const bool aok = grow < NN;
    const ushort* arp = (const ushort*)Ap + (size_t)grow * K + sk0;

    if constexpr (AT == 1) {
        for (int i = tid; i < K; i += 256) { s_sc[i] = scale[i]; s_sh[i] = shift[i]; }
        __syncthreads();
    }

    f32x4 acc[4][NF];
#pragma unroll
    for (int mi = 0; mi < 4; ++mi)
#pragma unroll
        for (int ni = 0; ni < NF; ++ni) acc[mi][ni] = (f32x4){0.f, 0.f, 0.f, 0.f};

    // prologue: stage tile 0
    uint4 av = make_uint4(0, 0, 0, 0);
    if (aok) av = *(const uint4*)arp;
    av = xform8<AT>(av, sk0, s_sc, s_sh);
    *(uint4*)&As[0][srow * LDA + sk0] = av;

    for (int t = 0; t < NT; ++t) {
        __syncthreads();                      // As[t&1] ready for all
        uint4 anext = make_uint4(0, 0, 0, 0);
        if (t + 1 < NT && aok)
            anext = *(const uint4*)(arp + (t + 1) * BK);   // issue early (overlaps MFMA)

        short8 bfv[NF];
#pragma unroll
        for (int ni = 0; ni < NF; ++ni)
            bfv[ni] = *(const short8*)(BT + (size_t)(wid * WN + ni * 16 + fr) * K + t * BK + fk);

        short8 af[4];
#pragma unroll
        for (int mi = 0; mi < 4; ++mi)
            af[mi] = *(const short8*)&As[t & 1][(mi * 16 + fr) * LDA + fk];

#pragma unroll
        for (int mi = 0; mi < 4; ++mi)
#pragma unroll
            for (int ni = 0; ni < NF; ++ni)
                acc[mi][ni] = __builtin_amdgcn_mfma_f32_16x16x32_bf16(af[mi], bfv[ni], acc[mi][ni], 0, 0, 0);

        if (t + 1 < NT) {                     // write-late into alternate buffer
            anext = xform8<AT>(anext, (t + 1) * BK + sk0, s_sc, s_sh);
            *(uint4*)&As[(t + 1) & 1][srow * LDA + sk0] = anext;
        }
    }

    float bv[NF];
#pragma unroll
    for (int ni = 0; ni < NF; ++ni) bv[ni] = bias[wid * WN + ni * 16 + fr];

    if constexpr (OUT == 1) {
        float* outf = (float*)Cp;
#pragma unroll
        for (int mi = 0; mi < 4; ++mi)
#pragma unroll
            for (int r = 0; r < 4; ++r) {
                int row = brow + mi * 16 + fq * 4 + r;
                if (row < NN) {
#pragma unroll
                    for (int ni = 0; ni < NF; ++ni) {
                        int c = wid * WN + ni * 16 + fr;
                        outf[(size_t)row * NOUT + c] = acc[mi][ni][r] + bv[ni];
                    }
                }
            }
    } else {
        ushort* outb = (ushort*)Cp;
#pragma unroll
        for (int mi = 0; mi < 4; ++mi)
#pragma unroll
            for (int r = 0; r < 4; ++r) {
                int row = brow + mi * 16 + fq * 4 + r;
                if (row < NN) {
#pragma unroll
                    for (int ni = 0; ni < NF; ++ni) {
                        int c = wid * WN + ni * 16 + fr;
                        outb[(size_t)row * NOUT + c] = f2bf(acc[mi][ni][r] + bv[ni]);
                    }
                }
            }
    }
}

// ================= BN statistics (uint4 loads, atomic-free) =================
template <int M>
__global__ __launch_bounds__(256) void k_bnpart(const ushort* __restrict__ X, float* __restrict__ partials) {
    constexpr int FG = M / 8, RP = 256 / FG;   // 8 feats/thread
    __shared__ float rs[RP * M];
    __shared__ float rq[RP * M];
    int fg = threadIdx.x % FG, r0 = threadIdx.x / FG;
    float s[8] = {0, 0, 0, 0, 0, 0, 0, 0}, q[8] = {0, 0, 0, 0, 0, 0, 0, 0};
    for (int n = blockIdx.x * RP + r0; n < NN; n += GBN * RP) {
        uint4 u = ((const uint4*)X)[(size_t)n * FG + fg];
        uint uu[4] = {u.x, u.y, u.z, u.w};
#pragma unroll
        for (int p = 0; p < 4; ++p) {
            float v0 = bfu2f(uu[p] & 0xffffu), v1 = bfhi2f(uu[p]);
            s[p * 2] += v0; q[p * 2] += v0 * v0;
            s[p * 2 + 1] += v1; q[p * 2 + 1] += v1 * v1;
        }
    }
    int f0 = fg * 8;
#pragma unroll
    for (int j = 0; j < 8; ++j) {
        rs[r0 * M + f0 + j] = s[j];
        rq[r0 * M + f0 + j] = q[j];
    }
    __syncthreads();
    for (int h = RP / 2; h; h >>= 1) {
        if (r0 < h) {
#pragma unroll
            for (int j = 0; j < 8; ++j) {
                rs[r0 * M + f0 + j] += rs[(r0 + h) * M + f0 + j];
                rq[r0 * M + f0 + j] += rq[(r0 + h) * M + f0 + j];
            }
        }
        __syncthreads();
    }
    if (threadIdx.x < M) {
        partials[(size_t)blockIdx.x * 2 * M + threadIdx.x] = rs[threadIdx.x];
        partials[(size_t)blockIdx.x * 2 * M + M + threadIdx.x] = rq[threadIdx.x];
    }
}

template <int M>
__global__ void k_bnred(const float* __restrict__ partials, const float* __restrict__ g,
                        const float* __restrict__ be, float* __restrict__ scale,
                        float* __restrict__ shift) {
    int f = threadIdx.x;
    if (f < M) {
        float s = 0.f, q = 0.f;
        for (int b = 0; b < GBN; ++b) {
            s += partials[(size_t)b * 2 * M + f];
            q += partials[(size_t)b * 2 * M + M + f];
        }
        float mu = s * (1.f / NN);
        float var = q * (1.f / NN) - mu * mu;
        float r = rsqrtf(var + EPS_BN);
        float sc = g[f] * r;
        scale[f] = sc;
        shift[f] = be[f] - mu * sc;
    }
}

// ================= launch =================
extern "C" void kernel_launch(void* const* d_in, const int* in_sizes, int n_in,
                              void* d_out, int out_size, void* d_ws, size_t ws_size,
                              hipStream_t stream) {
    const float* emb = (const float*)d_in[0];
    const int* eidx  = (const int*)d_in[1];
    const float* W1  = (const float*)d_in[2];
    const float* b1  = (const float*)d_in[3];
    const float* g1  = (const float*)d_in[4];
    const float* be1 = (const float*)d_in[5];
    const float* W2  = (const float*)d_in[6];
    const float* b2  = (const float*)d_in[7];
    const float* g2  = (const float*)d_in[8];
    const float* be2 = (const float*)d_in[9];
    const float* Wf  = (const float*)d_in[10];
    const float* bf  = (const float*)d_in[11];
    float* out = (float*)d_out;
    const int* srcv = eidx;
    const int* dstv = eidx + NE;

    char* w = (char*)d_ws;
    auto alloc = [&](size_t bytes) {
        char* p = w;
        w += (bytes + 255) / 256 * 256;
        return p;
    };
    int* cnt    = (int*)alloc((size_t)NN * 4);
    int* indptr = (int*)alloc((size_t)NN * 4);
    int* bcnt   = (int*)alloc((size_t)NBUCK * GA * 4);
    int* gcur   = (int*)alloc((size_t)NBUCK * GA * 4);
    int* bbase  = (int*)alloc((size_t)(NBUCK + 1) * 4);
    int* colb   = (int*)alloc((size_t)NE * 4);
    uint* bpair = (uint*)alloc((size_t)NE * 4);
    float* dinv = (float*)alloc((size_t)NN * 4);
    float* partials = (float*)alloc((size_t)GBN * 512 * 4);
    float* sc1 = (float*)alloc(128 * 4);
    float* sh1 = (float*)alloc(128 * 4);
    float* sc2 = (float*)alloc(256 * 4);
    float* sh2 = (float*)alloc(256 * 4);
    ushort* w1t = (ushort*)alloc((size_t)128 * 64 * 2);
    ushort* w2t = (ushort*)alloc((size_t)256 * 128 * 2);
    ushort* wft = (ushort*)alloc((size_t)256 * 256 * 2);
    ushort* slabA = (ushort*)alloc((size_t)NN * 128 * 2);   // embs -> H1 -> agg2
    ushort* slabB = (ushort*)alloc((size_t)NN * 128 * 2);   // aggE -> x2s
    ushort* H2 = (ushort*)alloc((size_t)NN * 256 * 2);

    ushort* embs = slabA;
    ushort* aggE = slabB;
    ushort* H1   = slabA;
    ushort* x2s  = slabB;
    ushort* agg2 = slabA;

    // ---- CSR build ----
    k_bhist<<<GA, 256, 0, stream>>>(dstv, bcnt);
    k_bscan<<<1, 1024, 0, stream>>>(bcnt, gcur, bbase);
    k_bscatter<<<GA, 256, 0, stream>>>(srcv, dstv, gcur, bpair);
    k_bcsr<<<NBUCK, 256, 0, stream>>>(bpair, bbase, colb, cnt, indptr, dinv);

    // ---- weights ----
    k_wtrans_all<<<(8192 + 32768 + 65536 + 255) / 256, 256, 0, stream>>>(W1, W2, Wf, w1t, w2t, wft);

    constexpr int GX = (NN + 63) / 64;   // 1563

    // ---- layer 1 ----
    k_semb<<<(NN * 16 + 255) / 256, 256, 0, stream>>>(emb, dinv, (uint2*)embs);
    k_agg64<<<NN, 64, 0, stream>>>(embs, indptr, cnt, colb, dinv, aggE);
    k_mgemm<64, 128, 2, 2><<<GX, 256, 0, stream>>>(aggE, w1t, H1, nullptr, nullptr, b1);
    k_bnpart<128><<<GBN, 256, 0, stream>>>(H1, partials);
    k_bnred<128><<<1, 256, 0, stream>>>(partials, g1, be1, sc1, sh1);

    // ---- layer 2 ----
    k_x2s<<<(NN * 16 + 255) / 256, 256, 0, stream>>>(H1, sc1, sh1, dinv, x2s);
    k_agg128<<<NN, 64, 0, stream>>>(x2s, indptr, cnt, colb, dinv, agg2);
    k_mgemm<128, 256, 2, 2><<<GX, 256, 0, stream>>>(agg2, w2t, H2, nullptr, nullptr, b2);
    k_bnpart<256><<<GBN, 256, 0, stream>>>(H2, partials);
    k_bnred<256><<<1, 256, 0, stream>>>(partials, g2, be2, sc2, sh2);

    // ---- final linear -> fp32 d_out ----
    k_mgemm<256, 256, 1, 1><<<GX, 256, 0, stream>>>(H2, wft, out, sc2, sh2, bf);
}

// Round 7
// 349.534 us; speedup vs baseline: 2.9662x; 1.0424x over previous
//
#include <hip/hip_runtime.h>

#define NN 100000
#define NE 1600000
constexpr float EPS_BN = 1e-5f;
constexpr float ALPHA = 0.01f;
constexpr int NBUCK = (NN + 127) / 128;     // 782 buckets of 128 nodes
constexpr int GA = 128;                     // bucket-pass blocks
constexpr int EPB = NE / GA;                // 12500 edges/block (exact)
constexpr int GX = (NN + 63) / 64;          // 1563 gemm blocks

typedef __attribute__((ext_vector_type(8))) short short8;
typedef __attribute__((ext_vector_type(4))) float f32x4;

// ---- bf16 helpers ----
__device__ __forceinline__ float bfu2f(uint lo16) {
    union { uint i; float f; } v; v.i = lo16 << 16; return v.f;
}
__device__ __forceinline__ float bfhi2f(uint u) {
    union { uint i; float f; } v; v.i = u & 0xffff0000u; return v.f;
}
__device__ __forceinline__ ushort f2bf(float f) {     // RNE
    union { float f; uint i; } v; v.f = f;
    return (ushort)((v.i + 0x7fffu + ((v.i >> 16) & 1u)) >> 16);
}

// ================= bucketed CSR build =================
__global__ __launch_bounds__(256) void k_bhist(const int* __restrict__ dstv, int* __restrict__ bcnt) {
    __shared__ int hist[NBUCK];
    for (int i = threadIdx.x; i < NBUCK; i += 256) hist[i] = 0;
    __syncthreads();
    int base = blockIdx.x * EPB;
    for (int i = threadIdx.x; i < EPB; i += 256)
        atomicAdd(&hist[dstv[base + i] >> 7], 1);
    __syncthreads();
    for (int i = threadIdx.x; i < NBUCK; i += 256)
        bcnt[blockIdx.x * NBUCK + i] = hist[i];
}

// totals per bucket (coalesced, multi-block)
__global__ __launch_bounds__(256) void k_btot(const int* __restrict__ bcnt, int* __restrict__ tot) {
    int b = blockIdx.x * 256 + threadIdx.x;
    if (b < NBUCK) {
        int t = 0;
        for (int k = 0; k < GA; ++k) t += bcnt[k * NBUCK + b];
        tot[b] = t;
    }
}

// scan 782 totals -> bbase (tiny single block)
__global__ __launch_bounds__(1024) void k_bscanT(const int* __restrict__ tot, int* __restrict__ bbase) {
    __shared__ int tmp[1024];
    int b = threadIdx.x;
    int v = (b < NBUCK) ? tot[b] : 0;
    tmp[b] = v;
    __syncthreads();
    for (int off = 1; off < 1024; off <<= 1) {
        int u = (b >= off) ? tmp[b - off] : 0;
        __syncthreads();
        tmp[b] += u;
        __syncthreads();
    }
    if (b < NBUCK) bbase[b] = tmp[b] - v;
    if (b == 0) bbase[NBUCK] = NE;
}

// per-(block,bucket) cursors (coalesced per k-iteration, multi-block)
__global__ __launch_bounds__(256) void k_bcur(const int* __restrict__ bcnt, const int* __restrict__ bbase,
                                              int* __restrict__ gcur) {
    int b = blockIdx.x * 256 + threadIdx.x;
    if (b < NBUCK) {
        int cur = bbase[b];
        for (int k = 0; k < GA; ++k) { gcur[k * NBUCK + b] = cur; cur += bcnt[k * NBUCK + b]; }
    }
}

__global__ __launch_bounds__(256) void k_bscatter(const int* __restrict__ srcv, const int* __restrict__ dstv,
                                                  const int* __restrict__ gcur, uint* __restrict__ bpair) {
    __shared__ int lcur[NBUCK];
    for (int i = threadIdx.x; i < NBUCK; i += 256) lcur[i] = gcur[blockIdx.x * NBUCK + i];
    __syncthreads();
    int base = blockIdx.x * EPB;
    for (int i = threadIdx.x; i < EPB; i += 256) {
        int d = dstv[base + i], s = srcv[base + i];
        int slot = atomicAdd(&lcur[d >> 7], 1);
        bpair[slot] = ((uint)(d & 127) << 17) | (uint)s;
    }
}

__global__ __launch_bounds__(256) void k_bcsr(const uint* __restrict__ bpair, const int* __restrict__ bbase,
                                              int* __restrict__ col, int* __restrict__ cnt,
                                              int* __restrict__ indptr, float* __restrict__ dinv) {
    __shared__ int h[128];
    __shared__ int off[128];
    int b = blockIdx.x, t = threadIdx.x;
    int p0 = bbase[b], p1 = bbase[b + 1];
    if (t < 128) h[t] = 0;
    __syncthreads();
    for (int i = p0 + t; i < p1; i += 256)
        atomicAdd(&h[bpair[i] >> 17], 1);
    __syncthreads();
    if (t < 128) off[t] = h[t];
    __syncthreads();
    for (int o = 1; o < 128; o <<= 1) {
        int u = 0;
        if (t < 128 && t >= o) u = off[t - o];
        __syncthreads();
        if (t < 128) off[t] += u;
        __syncthreads();
    }
    if (t < 128) {
        int st = p0 + off[t] - h[t];
        int node = b * 128 + t;
        if (node < NN) {
            indptr[node] = st;
            cnt[node] = h[t];
            dinv[node] = rsqrtf((float)(h[t] + 1));   // +1 self loop
        }
        off[t] = st;
    }
    __syncthreads();
    for (int i = p0 + t; i < p1; i += 256) {
        uint u = bpair[i];
        int slot = atomicAdd(&off[u >> 17], 1);
        col[slot] = (int)(u & 0x1FFFFu);
    }
}

// ================= all weights -> bf16 transposed [M][K], one launch =================
__global__ void k_wtrans_all(const float* __restrict__ W1, const float* __restrict__ W2,
                             const float* __restrict__ Wf, ushort* __restrict__ w1t,
                             ushort* __restrict__ w2t, ushort* __restrict__ wft) {
    int i = blockIdx.x * 256 + threadIdx.x;
    if (i < 8192) {                    // W1: 64x128 -> [128][64]
        int m = i / 64, k = i % 64;
        w1t[i] = f2bf(W1[(size_t)k * 128 + m]);
    } else if (i < 8192 + 32768) {     // W2: 128x256 -> [256][128]
        int j = i - 8192;
        int m = j / 128, k = j % 128;
        w2t[j] = f2bf(W2[(size_t)k * 256 + m]);
    } else if (i < 8192 + 32768 + 65536) {   // Wf: 256x256 -> [256][256]
        int j = i - 8192 - 32768;
        int m = j / 256, k = j % 256;
        wft[j] = f2bf(Wf[(size_t)k * 256 + m]);
    }
}

// ================= elementwise pre-passes =================
__global__ __launch_bounds__(256) void k_semb(const float* __restrict__ emb, const float* __restrict__ dinv,
                                              uint2* __restrict__ embs) {
    int i = blockIdx.x * 256 + threadIdx.x;   // uint2 index: 4 feats
    if (i >= NN * 16) return;
    int row = i >> 4;
    float dn = dinv[row];
    float4 f = ((const float4*)emb)[i];
    uint2 o;
    o.x = (uint)f2bf(f.x * dn) | ((uint)f2bf(f.y * dn) << 16);
    o.y = (uint)f2bf(f.z * dn) | ((uint)f2bf(f.w * dn) << 16);
    embs[i] = o;
}

__global__ __launch_bounds__(256) void k_x2s(const ushort* __restrict__ H1, const float* __restrict__ sc,
                                             const float* __restrict__ sh, const float* __restrict__ dinv,
                                             ushort* __restrict__ x2s) {
    int i = blockIdx.x * 256 + threadIdx.x;   // uint4 index: 8 feats
    if (i >= NN * 16) return;
    int row = i >> 4, f0 = (i & 15) * 8;
    float dn = dinv[row];
    uint4 u = ((const uint4*)H1)[i];
    uint uu[4] = {u.x, u.y, u.z, u.w};
    uint oo[4];
#pragma unroll
    for (int q = 0; q < 4; ++q) {
        int f = f0 + q * 2;
        float e0 = bfu2f(uu[q] & 0xffffu) * sc[f] + sh[f];
        float e1 = bfhi2f(uu[q]) * sc[f + 1] + sh[f + 1];
        e0 = ((e0 >= 0.f) ? e0 : ALPHA * e0) * dn;
        e1 = ((e1 >= 0.f) ? e1 : ALPHA * e1) * dn;
        oo[q] = (uint)f2bf(e0) | ((uint)f2bf(e1) << 16);
    }
    uint4 o; o.x = oo[0]; o.y = oo[1]; o.z = oo[2]; o.w = oo[3];
    ((uint4*)x2s)[i] = o;
}

// ================= CSR gather aggregation =================
__global__ __launch_bounds__(64) void k_agg64(const ushort* __restrict__ X, const int* __restrict__ indptr,
                                              const int* __restrict__ cnt, const int* __restrict__ col,
                                              const float* __restrict__ dinv, ushort* __restrict__ out) {
    int n = blockIdx.x, t = threadIdx.x;
    int t2 = t & 31, h = t >> 5;
    __shared__ int sc[64];
    int start = indptr[n], c = cnt[n];
    const uint* Xu = (const uint*)X;
    float a0 = 0.f, a1 = 0.f;
    if (h == 0) {
        uint u = Xu[(size_t)n * 32 + t2];
        a0 = bfu2f(u & 0xffffu); a1 = bfhi2f(u);
    }
    for (int base = 0; base < c; base += 64) {
        int m = min(64, c - base);
        if (t < m) sc[t] = col[start + base + t];
        __syncthreads();
#pragma unroll 2
        for (int j = h; j < m; j += 2) {
            uint v = Xu[(size_t)sc[j] * 32 + t2];
            a0 += bfu2f(v & 0xffffu); a1 += bfhi2f(v);
        }
        __syncthreads();
    }
    a0 += __shfl_xor(a0, 32);
    a1 += __shfl_xor(a1, 32);
    if (h == 0) {
        float dn = dinv[n];
        ((uint*)out)[(size_t)n * 32 + t2] = (uint)f2bf(a0 * dn) | ((uint)f2bf(a1 * dn) << 16);
    }
}

__global__ __launch_bounds__(64) void k_agg128(const ushort* __restrict__ X, const int* __restrict__ indptr,
                                               const int* __restrict__ cnt, const int* __restrict__ col,
                                               const float* __restrict__ dinv, ushort* __restrict__ out) {
    int n = blockIdx.x, t = threadIdx.x;
    __shared__ int sc[64];
    int start = indptr[n], c = cnt[n];
    const uint* Xu = (const uint*)X;
    uint u = Xu[(size_t)n * 64 + t];
    float a0 = bfu2f(u & 0xffffu), a1 = bfhi2f(u);
    float b0 = 0.f, b1 = 0.f;
    for (int base = 0; base < c; base += 64) {
        int m = min(64, c - base);
        if (t < m) sc[t] = col[start + base + t];
        __syncthreads();
        int j = 0;
#pragma unroll 2
        for (; j + 2 <= m; j += 2) {
            uint v0 = Xu[(size_t)sc[j] * 64 + t];
            uint v1 = Xu[(size_t)sc[j + 1] * 64 + t];
            a0 += bfu2f(v0 & 0xffffu); a1 += bfhi2f(v0);
            b0 += bfu2f(v1 & 0xffffu); b1 += bfhi2f(v1);
        }
        if (j < m) {
            uint v = Xu[(size_t)sc[j] * 64 + t];
            a0 += bfu2f(v & 0xffffu); a1 += bfhi2f(v);
        }
        __syncthreads();
    }
    a0 += b0; a1 += b1;
    float dn = dinv[n];
    ((uint*)out)[(size_t)n * 64 + t] = (uint)f2bf(a0 * dn) | ((uint)f2bf(a1 * dn) << 16);
}

// ================= MFMA bf16 GEMM: BM=64, no B-LDS, dbuf A, fused BN-stats =================
// AT 1: apply leaky(A*sc+sh) on stage   AT 2: A bf16 raw
// OUT 1: C = fp32(acc + bias[col])      OUT 2: C = bf16(acc + bias[col])
// STATS: also write per-block (sum, sumsq) partials[blk][2*NOUT]
template <int AT>
__device__ __forceinline__ uint4 xform8(uint4 u, int kbase, const float* s_sc, const float* s_sh) {
    if constexpr (AT == 1) {
        uint uu[4] = {u.x, u.y, u.z, u.w};
        uint oo[4];
#pragma unroll
        for (int q = 0; q < 4; ++q) {
            int kq = kbase + q * 2;
            float e0 = bfu2f(uu[q] & 0xffffu) * s_sc[kq] + s_sh[kq];
            float e1 = bfhi2f(uu[q]) * s_sc[kq + 1] + s_sh[kq + 1];
            e0 = (e0 >= 0.f) ? e0 : ALPHA * e0;
            e1 = (e1 >= 0.f) ? e1 : ALPHA * e1;
            oo[q] = (uint)f2bf(e0) | ((uint)f2bf(e1) << 16);
        }
        return make_uint4(oo[0], oo[1], oo[2], oo[3]);
    } else {
        return u;
    }
}

template <int K, int NOUT, int AT, int OUT, bool STATS>
__global__ __launch_bounds__(256) void k_mgemm(
        const void* __restrict__ Ap, const ushort* __restrict__ BT, void* __restrict__ Cp,
        const float* __restrict__ scale, const float* __restrict__ shift,
        const float* __restrict__ bias, float* __restrict__ partials) {
    constexpr int BM = 64, BK = 32, LDA = 40;
    constexpr int WN = NOUT / 4;          // wave col width: 32 or 64
    constexpr int NF = WN / 16;           // col frags/wave: 2 or 4
    constexpr int NT = K / BK;
    __shared__ ushort As[2][BM * LDA];
    __shared__ float s_sc[K];
    __shared__ float s_sh[K];

    int tid = threadIdx.x;
    int brow = blockIdx.x * BM;
    int lane = tid & 63, wid = tid >> 6;
    int fr = lane & 15, fq = lane >> 4;
    int fk = fq * 8;

    const int srow = tid >> 2, sk0 = (tid & 3) * 8;   // A-stage: 8 bf16/thread
    const int grow = brow + srow;
    const bool aok = grow < NN;
    const ushort* arp = (const ushort*)Ap + (size_t)grow * K + sk0;

    if constexpr (AT == 1) {
        for (int i = tid; i < K; i += 256) { s_sc[i] = scale[i]; s_sh[i] = shift[i]; }
        __syncthreads();
    }

    f32x4 acc[4][NF];
#pragma unroll
    for (int mi = 0; mi < 4; ++mi)
#pragma unroll
        for (int ni = 0; ni < NF; ++ni) acc[mi][ni] = (f32x4){0.f, 0.f, 0.f, 0.f};

    // prologue: stage tile 0
    uint4 av = make_uint4(0, 0, 0, 0);
    if (aok) av = *(const uint4*)arp;
    av = xform8<AT>(av, sk0, s_sc, s_sh);
    *(uint4*)&As[0][srow * LDA + sk0] = av;

    for (int t = 0; t < NT; ++t) {
        __syncthreads();                      // As[t&1] ready for all
        uint4 anext = make_uint4(0, 0, 0, 0);
        if (t + 1 < NT && aok)
            anext = *(const uint4*)(arp + (t + 1) * BK);   // issue early (overlaps MFMA)

        short8 bfv[NF];
#pragma unroll
        for (int ni = 0; ni < NF; ++ni)
            bfv[ni] = *(const short8*)(BT + (size_t)(wid * WN + ni * 16 + fr) * K + t * BK + fk);

        short8 af[4];
#pragma unroll
        for (int mi = 0; mi < 4; ++mi)
            af[mi] = *(const short8*)&As[t & 1][(mi * 16 + fr) * LDA + fk];

#pragma unroll
        for (int mi = 0; mi < 4; ++mi)
#pragma unroll
            for (int ni = 0; ni < NF; ++ni)
                acc[mi][ni] = __builtin_amdgcn_mfma_f32_16x16x32_bf16(af[mi], bfv[ni], acc[mi][ni], 0, 0, 0);

        if (t + 1 < NT) {                     // write-late into alternate buffer
            anext = xform8<AT>(anext, (t + 1) * BK + sk0, s_sc, s_sh);
            *(uint4*)&As[(t + 1) & 1][srow * LDA + sk0] = anext;
        }
    }

    float bv[NF];
#pragma unroll
    for (int ni = 0; ni < NF; ++ni) bv[ni] = bias[wid * WN + ni * 16 + fr];

    float sv[NF], qv[NF];
#pragma unroll
    for (int ni = 0; ni < NF; ++ni) { sv[ni] = 0.f; qv[ni] = 0.f; }

#pragma unroll
    for (int mi = 0; mi < 4; ++mi)
#pragma unroll
        for (int r = 0; r < 4; ++r) {
            int row = brow + mi * 16 + fq * 4 + r;
            if (row < NN) {
#pragma unroll
                for (int ni = 0; ni < NF; ++ni) {
                    float x = acc[mi][ni][r] + bv[ni];
                    int c = wid * WN + ni * 16 + fr;
                    if constexpr (OUT == 1)
                        ((float*)Cp)[(size_t)row * NOUT + c] = x;
                    else
                        ((ushort*)Cp)[(size_t)row * NOUT + c] = f2bf(x);
                    if constexpr (STATS) { sv[ni] += x; qv[ni] += x * x; }
                }
            }
        }

    if constexpr (STATS) {
        // reduce over fq groups (lanes fr, fr+16, fr+32, fr+48)
#pragma unroll
        for (int ni = 0; ni < NF; ++ni) {
            sv[ni] += __shfl_down(sv[ni], 32); qv[ni] += __shfl_down(qv[ni], 32);
            sv[ni] += __shfl_down(sv[ni], 16); qv[ni] += __shfl_down(qv[ni], 16);
        }
        if (fq == 0) {
            float* pb = partials + (size_t)blockIdx.x * 2 * NOUT;
#pragma unroll
            for (int ni = 0; ni < NF; ++ni) {
                int c = wid * WN + ni * 16 + fr;
                pb[c] = sv[ni];
                pb[NOUT + c] = qv[ni];
            }
        }
    }
}

// ================= BN reduce: partials[GX][2M] -> scale/shift =================
// grid: M/16 blocks, 256 threads = 16 b-lanes x 16 features
template <int M>
__global__ __launch_bounds__(256) void k_bnred(const float* __restrict__ partials, const float* __restrict__ g,
                                               const float* __restrict__ be, float* __restrict__ scale,
                                               float* __restrict__ shift) {
    int tid = threadIdx.x;
    int fl = tid & 15, bl = tid >> 4;
    int f = blockIdx.x * 16 + fl;
    float s = 0.f, q = 0.f;
    for (int b = bl; b < GX; b += 16) {
        s += partials[(size_t)b * 2 * M + f];
        q += partials[(size_t)b * 2 * M + M + f];
    }
    __shared__ float rs[256], rq[256];
    rs[tid] = s; rq[tid] = q;
    __syncthreads();
    for (int h = 128; h >= 16; h >>= 1) {
        if (tid < h) { rs[tid] += rs[tid + h]; rq[tid] += rq[tid + h]; }
        __syncthreads();
    }
    if (tid < 16) {
        float su = rs[tid], qu = rq[tid];
        float mu = su * (1.f / NN);
        float var = qu * (1.f / NN) - mu * mu;
        float r = rsqrtf(var + EPS_BN);
        float sc = g[f] * r;
        scale[f] = sc;
        shift[f] = be[f] - mu * sc;
    }
}

// ================= launch =================
extern "C" void kernel_launch(void* const* d_in, const int* in_sizes, int n_in,
                              void* d_out, int out_size, void* d_ws, size_t ws_size,
                              hipStream_t stream) {
    const float* emb = (const float*)d_in[0];
    const int* eidx  = (const int*)d_in[1];
    const float* W1  = (const float*)d_in[2];
    const float* b1  = (const float*)d_in[3];
    const float* g1  = (const float*)d_in[4];
    const float* be1 = (const float*)d_in[5];
    const float* W2  = (const float*)d_in[6];
    const float* b2  = (const float*)d_in[7];
    const float* g2  = (const float*)d_in[8];
    const float* be2 = (const float*)d_in[9];
    const float* Wf  = (const float*)d_in[10];
    const float* bf  = (const float*)d_in[11];
    float* out = (float*)d_out;
    const int* srcv = eidx;
    const int* dstv = eidx + NE;

    char* w = (char*)d_ws;
    auto alloc = [&](size_t bytes) {
        char* p = w;
        w += (bytes + 255) / 256 * 256;
        return p;
    };
    int* cnt    = (int*)alloc((size_t)NN * 4);
    int* indptr = (int*)alloc((size_t)NN * 4);
    int* bcnt   = (int*)alloc((size_t)NBUCK * GA * 4);
    int* gcur   = (int*)alloc((size_t)NBUCK * GA * 4);
    int* tot    = (int*)alloc((size_t)NBUCK * 4);
    int* bbase  = (int*)alloc((size_t)(NBUCK + 1) * 4);
    int* colb   = (int*)alloc((size_t)NE * 4);
    uint* bpair = (uint*)alloc((size_t)NE * 4);
    float* dinv = (float*)alloc((size_t)NN * 4);
    float* partials = (float*)alloc((size_t)GX * 512 * 4);
    float* sc1 = (float*)alloc(128 * 4);
    float* sh1 = (float*)alloc(128 * 4);
    float* sc2 = (float*)alloc(256 * 4);
    float* sh2 = (float*)alloc(256 * 4);
    ushort* w1t = (ushort*)alloc((size_t)128 * 64 * 2);
    ushort* w2t = (ushort*)alloc((size_t)256 * 128 * 2);
    ushort* wft = (ushort*)alloc((size_t)256 * 256 * 2);
    ushort* slabA = (ushort*)alloc((size_t)NN * 128 * 2);   // embs -> H1 -> agg2
    ushort* slabB = (ushort*)alloc((size_t)NN * 128 * 2);   // aggE -> x2s
    ushort* H2 = (ushort*)alloc((size_t)NN * 256 * 2);

    ushort* embs = slabA;
    ushort* aggE = slabB;
    ushort* H1   = slabA;
    ushort* x2s  = slabB;
    ushort* agg2 = slabA;

    constexpr int GB4 = (NBUCK + 255) / 256;   // 4

    // ---- CSR build ----
    k_bhist<<<GA, 256, 0, stream>>>(dstv, bcnt);
    k_btot<<<GB4, 256, 0, stream>>>(bcnt, tot);
    k_bscanT<<<1, 1024, 0, stream>>>(tot, bbase);
    k_bcur<<<GB4, 256, 0, stream>>>(bcnt, bbase, gcur);
    k_bscatter<<<GA, 256, 0, stream>>>(srcv, dstv, gcur, bpair);
    k_bcsr<<<NBUCK, 256, 0, stream>>>(bpair, bbase, colb, cnt, indptr, dinv);

    // ---- weights ----
    k_wtrans_all<<<(8192 + 32768 + 65536 + 255) / 256, 256, 0, stream>>>(W1, W2, Wf, w1t, w2t, wft);

    // ---- layer 1 ----
    k_semb<<<(NN * 16 + 255) / 256, 256, 0, stream>>>(emb, dinv, (uint2*)embs);
    k_agg64<<<NN, 64, 0, stream>>>(embs, indptr, cnt, colb, dinv, aggE);
    k_mgemm<64, 128, 2, 2, true><<<GX, 256, 0, stream>>>(aggE, w1t, H1, nullptr, nullptr, b1, partials);
    k_bnred<128><<<8, 256, 0, stream>>>(partials, g1, be1, sc1, sh1);

    // ---- layer 2 ----
    k_x2s<<<(NN * 16 + 255) / 256, 256, 0, stream>>>(H1, sc1, sh1, dinv, x2s);
    k_agg128<<<NN, 64, 0, stream>>>(x2s, indptr, cnt, colb, dinv, agg2);
    k_mgemm<128, 256, 2, 2, true><<<GX, 256, 0, stream>>>(agg2, w2t, H2, nullptr, nullptr, b2, partials);
    k_bnred<256><<<16, 256, 0, stream>>>(partials, g2, be2, sc2, sh2);

    // ---- final linear -> fp32 d_out ----
    k_mgemm<256, 256, 1, 1, false><<<GX, 256, 0, stream>>>(H2, wft, out, sc2, sh2, bf, nullptr);
}